// Round 15
// baseline (166.296 us; speedup 1.0000x reference)
//
#include <hip/hip_runtime.h>
#include <hip/hip_bf16.h>

#define B_ 2
#define N_ 512
#define DS_ 384
#define DP_ 128
#define H_ 16
#define DH_ 64
#define DI_ 1024
#define MAXSEQ 2048
#define PAD 8

typedef float f32x4 __attribute__((ext_vector_type(4)));
typedef short bf16x8 __attribute__((ext_vector_type(8)));

__device__ __forceinline__ unsigned short f2b(float f) {
    unsigned int u = __builtin_bit_cast(unsigned int, f);
    u += 0x7FFFu + ((u >> 16) & 1u);
    return (unsigned short)(u >> 16);
}
__device__ __forceinline__ float b2f(unsigned short s) {
    unsigned int u = ((unsigned int)s) << 16;
    return __builtin_bit_cast(float, u);
}

// XOR swizzle: byte-column ^ ((row&7)<<4). Applied on BOTH write and read.
#define SW(row, bc) ((bc) ^ (((row) & 7) << 4))

// ---- k_pre: bias blocks (bid<2048, 4 tiles each) + transposes (bid>=2048) --
// Bias v7: grid-stride 4 tiles/block + register prefetch of next tile during
// compute (keeps loads in flight through the compute phase -> read MLP).
__global__ __launch_bounds__(256) void k_pre(const float* __restrict__ pw,
                                             const float* __restrict__ abb,
                                             const float* __restrict__ gamma,
                                             const float* __restrict__ beta,
                                             const float* __restrict__ wb,
                                             const float* __restrict__ wq,
                                             const float* __restrict__ wk,
                                             const float* __restrict__ wv,
                                             const float* __restrict__ wg,
                                             const float* __restrict__ wo,
                                             unsigned short* __restrict__ Wt,
                                             unsigned short* __restrict__ Wot,
                                             unsigned short* __restrict__ biasP) {
    __shared__ float Xs[64 * 128];                          // 32 KB (also transpose tile)
    __shared__ float rsum[4][16] __attribute__((aligned(16)));
    __shared__ float rsq[4][16] __attribute__((aligned(16)));
    int bid = blockIdx.x;
    int t = threadIdx.x;

    if (bid >= 2048) {                  // ---- transpose path ----
        int tid = bid - 2048;
        int z = tid / 384, r = tid % 384;
        const float* in; unsigned short* out; int C, Rr, c0, r0;
        if (z < 4) {
            in = (z == 0) ? wq : (z == 1) ? wk : (z == 2) ? wv : wg;
            out = Wt + (long)z * 1024 * 384;
            C = 1024; Rr = 384;
            c0 = (r & 31) * 32; r0 = (r >> 5) * 32;
        } else {
            in = wo; out = Wot; C = 384; Rr = 1024;
            c0 = (r % 12) * 32; r0 = (r / 12) * 32;
        }
        float (*tile)[33] = (float(*)[33])Xs;
        int tx = t & 31, ty = t >> 5;
        #pragma unroll
        for (int i = ty; i < 32; i += 8)
            tile[i][tx] = in[(long)(r0 + i) * C + (c0 + tx)];
        __syncthreads();
        #pragma unroll
        for (int i = ty; i < 32; i += 8)
            out[(long)(c0 + i) * Rr + (r0 + tx)] = f2b(tile[tx][i]);
        return;
    }

    // ---- bias path ----
    int w = t >> 6, lane = t & 63;
    int lane15 = lane & 15, kg = lane >> 4;

    // prep once per block (L2-hot 8KB wb): gb[kk] + sh/th, shuffle-reduced
    float shp = 0.f, thp = 0.f;
    bf16x8 gb[4];
    #pragma unroll
    for (int kk = 0; kk < 4; ++kk) {
        bf16x8 a;
        unsigned short* ap = (unsigned short*)&a;
        #pragma unroll
        for (int e = 0; e < 8; ++e) {
            int d = kk * 32 + kg * 8 + e;
            float wv_ = wb[d * 16 + lane15];
            float gv = gamma[d];
            ap[e] = f2b(gv * wv_);
            shp = fmaf(gv, wv_, shp);
            thp = fmaf(beta[d], wv_, thp);
        }
        gb[kk] = a;
    }
    shp += __shfl_xor(shp, 16); shp += __shfl_xor(shp, 32);
    thp += __shfl_xor(thp, 16); thp += __shfl_xor(thp, 32);
    float sh = shp, th = thp;

    // prefetch tile 0 into registers
    uint4 rg[8];
    {
        const char* src0 = (const char*)pw + ((long)bid << 15);
        #pragma unroll
        for (int c = 0; c < 8; ++c)
            rg[c] = *(const uint4*)(src0 + c * 4096 + t * 16);
    }

    char* lds = (char*)Xs;
    for (int k = 0; k < 4; ++k) {
        long tile = (long)bid + (long)k * 2048;
        long p0 = tile * 64;
        int i_blk = (int)((p0 >> 9) & (N_ - 1));
        int j0 = (int)(p0 & (N_ - 1));
        long bb = p0 >> 18;

        __syncthreads();                // Xs free (previous tile consumed)
        #pragma unroll
        for (int c = 0; c < 8; ++c) {
            int L = c * 4096 + t * 16;
            int row = L >> 9, b = L & 511;
            *(uint4*)(lds + (row << 9) + (b ^ ((row & 7) << 4))) = rg[c];
        }
        if (k < 3) {                    // issue next tile's loads NOW (in flight
            const char* srcn = (const char*)pw + ((tile + 2048) << 15);
            #pragma unroll                // through barrier + compute below)
            for (int c = 0; c < 8; ++c)
                rg[c] = *(const uint4*)(srcn + c * 4096 + t * 16);
        }
        __syncthreads();                // Xs ready

        int row = w * 16 + lane15;
        const char* rbase = lds + (row << 9);
        int sw = (lane15 & 7) << 4;
        f32x4 xa[4], xb4[4];
        #pragma unroll
        for (int kk = 0; kk < 4; ++kk) {
            int b0 = kk * 128 + kg * 32;
            xa[kk]  = *(const f32x4*)(rbase + ((b0) ^ sw));
            xb4[kk] = *(const f32x4*)(rbase + ((b0 + 16) ^ sw));
        }
        float s = 0.f, q = 0.f;
        #pragma unroll
        for (int kk = 0; kk < 4; ++kk) {
            s += xa[kk][0] + xa[kk][1] + xa[kk][2] + xa[kk][3];
            s += xb4[kk][0] + xb4[kk][1] + xb4[kk][2] + xb4[kk][3];
            #pragma unroll
            for (int e = 0; e < 4; ++e) {
                q = fmaf(xa[kk][e], xa[kk][e], q);
                q = fmaf(xb4[kk][e], xb4[kk][e], q);
            }
        }
        s += __shfl_xor(s, 16); s += __shfl_xor(s, 32);
        q += __shfl_xor(q, 16); q += __shfl_xor(q, 32);
        if (lane < 16) { rsum[w][lane15] = s; rsq[w][lane15] = q; }

        f32x4 acc = {};
        #pragma unroll
        for (int kk = 0; kk < 4; ++kk) {
            bf16x8 a;
            unsigned short* ap = (unsigned short*)&a;
            ap[0] = f2b(xa[kk][0]);  ap[1] = f2b(xa[kk][1]);
            ap[2] = f2b(xa[kk][2]);  ap[3] = f2b(xa[kk][3]);
            ap[4] = f2b(xb4[kk][0]); ap[5] = f2b(xb4[kk][1]);
            ap[6] = f2b(xb4[kk][2]); ap[7] = f2b(xb4[kk][3]);
            acc = __builtin_amdgcn_mfma_f32_16x16x32_bf16(a, gb[kk], acc, 0, 0, 0);
        }
        int jr = w * 16 + kg * 4;
        float4 rs = *(const float4*)&rsum[w][kg * 4];
        float4 rq = *(const float4*)&rsq[w][kg * 4];
        float4 av = *(const float4*)(abb + (long)i_blk * MAXSEQ + j0 + jr);
        unsigned short* planeBase = biasP + ((bb * H_ + lane15) * N_ + i_blk) * N_ + j0;
        ushort4 res;
        float mu, var;
        mu = rs.x * (1.f / DP_); var = fmaf(rq.x, 1.f / DP_, -mu * mu);
        res.x = f2b(fmaf(rsqrtf(var + 1e-5f), acc[0] - mu * sh, th + av.x));
        mu = rs.y * (1.f / DP_); var = fmaf(rq.y, 1.f / DP_, -mu * mu);
        res.y = f2b(fmaf(rsqrtf(var + 1e-5f), acc[1] - mu * sh, th + av.y));
        mu = rs.z * (1.f / DP_); var = fmaf(rq.z, 1.f / DP_, -mu * mu);
        res.z = f2b(fmaf(rsqrtf(var + 1e-5f), acc[2] - mu * sh, th + av.z));
        mu = rs.w * (1.f / DP_); var = fmaf(rq.w, 1.f / DP_, -mu * mu);
        res.w = f2b(fmaf(rsqrtf(var + 1e-5f), acc[3] - mu * sh, th + av.w));
        *(ushort4*)(planeBase + jr) = res;
    }
}

// ---------------- QKVG projection GEMM (M=1024, N=4096, K=384) --------------
// 64x128 tiles, 512 blocks (2/CU). Q pre-scaled by 0.125.
__global__ __launch_bounds__(256) void k_proj(const float* __restrict__ X,
                                              const unsigned short* __restrict__ Wt,
                                              unsigned short* __restrict__ Qb,
                                              unsigned short* __restrict__ Kb,
                                              unsigned short* __restrict__ Vt,
                                              unsigned short* __restrict__ Xg) {
    __shared__ unsigned short As[64][64 + PAD];
    __shared__ unsigned short Bs[128][64 + PAD];
    int m0 = blockIdx.x * 64;
    int n0 = blockIdx.y * 128;
    int t = threadIdx.x;
    int wave = t >> 6, lane = t & 63;
    int wr = wave >> 1, wc = wave & 1;
    int lane15 = lane & 15, kg = lane >> 4;
    int rA = t >> 2, qA = t & 3;
    int rB = t >> 1, hB = t & 1;
    f32x4 acc[2][4] = {};
    for (int k0 = 0; k0 < DS_; k0 += 64) {
        __syncthreads();
        {
            const float4* srcA = (const float4*)(X + (long)(m0 + rA) * DS_ + k0 + qA * 16);
            unsigned short* dstA = &As[rA][qA * 16];
            #pragma unroll
            for (int ii = 0; ii < 4; ++ii) {
                float4 v = srcA[ii];
                dstA[ii * 4 + 0] = f2b(v.x); dstA[ii * 4 + 1] = f2b(v.y);
                dstA[ii * 4 + 2] = f2b(v.z); dstA[ii * 4 + 3] = f2b(v.w);
            }
            const uint4* srcB = (const uint4*)(Wt + (long)(n0 + rB) * DS_ + k0 + hB * 32);
            uint4* dstB = (uint4*)&Bs[rB][hB * 32];
            dstB[0] = srcB[0]; dstB[1] = srcB[1]; dstB[2] = srcB[2]; dstB[3] = srcB[3];
        }
        __syncthreads();
        #pragma unroll
        for (int ks = 0; ks < 2; ++ks) {
            bf16x8 a[2], bbv[4];
            #pragma unroll
            for (int mf = 0; mf < 2; ++mf)
                a[mf] = *(const bf16x8*)&As[wr * 32 + mf * 16 + lane15][ks * 32 + kg * 8];
            #pragma unroll
            for (int nf = 0; nf < 4; ++nf)
                bbv[nf] = *(const bf16x8*)&Bs[wc * 64 + nf * 16 + lane15][ks * 32 + kg * 8];
            #pragma unroll
            for (int mf = 0; mf < 2; ++mf)
                #pragma unroll
                for (int nf = 0; nf < 4; ++nf)
                    acc[mf][nf] = __builtin_amdgcn_mfma_f32_16x16x32_bf16(a[mf], bbv[nf], acc[mf][nf], 0, 0, 0);
        }
    }
    int p = n0 >> 10;
    int lgrp = lane >> 4;
    #pragma unroll
    for (int mf = 0; mf < 2; ++mf) {
        #pragma unroll
        for (int nf = 0; nf < 4; ++nf) {
            int col = n0 + wc * 64 + nf * 16 + lane15;
            int ch = col & 1023;
            int h = ch >> 6, dh = ch & 63;
            int row0 = m0 + wr * 32 + mf * 16 + lgrp * 4;
            if (p == 0 || p == 1) {
                unsigned short* base = (p == 0) ? Qb : Kb;
                float scl = (p == 0) ? 0.125f : 1.0f;
                #pragma unroll
                for (int rr = 0; rr < 4; ++rr) {
                    int rowx = row0 + rr;
                    int b = rowx >> 9, n = rowx & 511;
                    base[(((long)(b * 16 + h)) * 512 + n) * 64 + dh] = f2b(acc[mf][nf][rr] * scl);
                }
            } else if (p == 2) {
                int b = row0 >> 9, n = row0 & 511;
                ushort4 v;
                v.x = f2b(acc[mf][nf][0]); v.y = f2b(acc[mf][nf][1]);
                v.z = f2b(acc[mf][nf][2]); v.w = f2b(acc[mf][nf][3]);
                *(ushort4*)&Vt[(((long)(b * 16 + h)) * 64 + dh) * 512 + n] = v;
            } else {
                #pragma unroll
                for (int rr = 0; rr < 4; ++rr) {
                    int rowx = row0 + rr;
                    Xg[(long)rowx * 1024 + ch] = f2b(acc[mf][nf][rr]);
                }
            }
        }
    }
}

// ---------------- fused flash attention -------------------------------------
// v4 (R14): pad-free XOR-swizzled LDS + Ps/Oscr union -> 64.5 KB -> 2 blocks/CU.
__global__ __launch_bounds__(512) void k_flash(const unsigned short* __restrict__ Qb,
                                               const unsigned short* __restrict__ Kb,
                                               const unsigned short* __restrict__ Vt,
                                               const unsigned short* __restrict__ biasP,
                                               const unsigned short* __restrict__ Xg,
                                               unsigned short* __restrict__ Og) {
    __shared__ unsigned short Kt[2][64][64];   // 16 KB, swizzled
    __shared__ unsigned short Vs[2][64][64];   // 16 KB, swizzled
    __shared__ unsigned short Bt[2][64][64];   // 16 KB, swizzled
    __shared__ char PsOscr[16384];             // Ps (main loop) ∪ Oscr (merge)
    __shared__ float Mscr[4][16], Lscr[4][16];
    unsigned short (*Ps)[16][64] = (unsigned short(*)[16][64])PsOscr;
    float (*Oscr)[16][64] = (float(*)[16][64])PsOscr;
    int bh = blockIdx.y;
    int b = bh >> 4, h = bh & 15;
    int i0 = blockIdx.x * 64;
    int t = threadIdx.x, w = t >> 6, lane = t & 63;
    int g = w & 3, jg = w >> 2;
    int lane15 = lane & 15, lgrp = lane >> 4;
    int tl = t & 255;
    int rs_ = tl >> 3, cs_ = tl & 7;

    bf16x8 qf[2];
    #pragma unroll
    for (int kk = 0; kk < 2; ++kk)
        qf[kk] = *(const bf16x8*)&Qb[((long)bh * 512 + i0 + g * 16 + lane15) * 64 + kk * 32 + lgrp * 8];

    float m_run = -1e30f, l_run = 0.f;
    f32x4 o[4] = {};

    for (int jtl = 0; jtl < 4; ++jtl) {
        int j0 = (jg * 4 + jtl) * 64;
        __syncthreads();
        {
            int r2 = rs_ + 32;
            *(uint4*)((char*)&Kt[jg][rs_][0] + SW(rs_, cs_ * 16)) =
                *(const uint4*)&Kb[((long)bh * 512 + j0 + rs_) * 64 + cs_ * 8];
            *(uint4*)((char*)&Vs[jg][rs_][0] + SW(rs_, cs_ * 16)) =
                *(const uint4*)&Vt[((long)bh * 64 + rs_) * 512 + j0 + cs_ * 8];
            *(uint4*)((char*)&Bt[jg][rs_][0] + SW(rs_, cs_ * 16)) =
                *(const uint4*)&biasP[((long)bh * 512 + i0 + rs_) * 512 + j0 + cs_ * 8];
            *(uint4*)((char*)&Kt[jg][r2][0] + SW(r2, cs_ * 16)) =
                *(const uint4*)&Kb[((long)bh * 512 + j0 + r2) * 64 + cs_ * 8];
            *(uint4*)((char*)&Vs[jg][r2][0] + SW(r2, cs_ * 16)) =
                *(const uint4*)&Vt[((long)bh * 64 + r2) * 512 + j0 + cs_ * 8];
            *(uint4*)((char*)&Bt[jg][r2][0] + SW(r2, cs_ * 16)) =
                *(const uint4*)&biasP[((long)bh * 512 + i0 + r2) * 512 + j0 + cs_ * 8];
        }
        __syncthreads();

        f32x4 s[4];
        #pragma unroll
        for (int nf = 0; nf < 4; ++nf) {
            f32x4 z = {};
            #pragma unroll
            for (int kk = 0; kk < 2; ++kk) {
                bf16x8 af = *(const bf16x8*)((const char*)&Kt[jg][nf * 16 + lane15][0] +
                                             SW(lane15, kk * 64 + lgrp * 16));
                z = __builtin_amdgcn_mfma_f32_16x16x32_bf16(af, qf[kk], z, 0, 0, 0);
            }
            s[nf] = z;
        }
        #pragma unroll
        for (int nf = 0; nf < 4; ++nf) {
            ushort4 bv = *(const ushort4*)((const char*)&Bt[jg][g * 16 + lane15][0] +
                                           SW(lane15, nf * 32 + lgrp * 8));
            s[nf][0] += b2f(bv.x); s[nf][1] += b2f(bv.y);
            s[nf][2] += b2f(bv.z); s[nf][3] += b2f(bv.w);
        }

        float pmax = s[0][0];
        #pragma unroll
        for (int nf = 0; nf < 4; ++nf)
            #pragma unroll
            for (int rr = 0; rr < 4; ++rr) pmax = fmaxf(pmax, s[nf][rr]);
        pmax = fmaxf(pmax, __shfl_xor(pmax, 16));
        pmax = fmaxf(pmax, __shfl_xor(pmax, 32));
        float m_new = fmaxf(m_run, pmax);
        float scale = __expf(m_run - m_new);
        float psum = 0.f;
        #pragma unroll
        for (int nf = 0; nf < 4; ++nf)
            #pragma unroll
            for (int rr = 0; rr < 4; ++rr) {
                s[nf][rr] = __expf(s[nf][rr] - m_new);
                psum += s[nf][rr];
            }
        psum += __shfl_xor(psum, 16);
        psum += __shfl_xor(psum, 32);
        l_run = l_run * scale + psum;
        m_run = m_new;
        #pragma unroll
        for (int rr = 0; rr < 4; ++rr) {
            float sc = __shfl(scale, lgrp * 4 + rr);
            #pragma unroll
            for (int nf = 0; nf < 4; ++nf) o[nf][rr] *= sc;
        }
        #pragma unroll
        for (int nf = 0; nf < 4; ++nf) {
            ushort4 pv_;
            pv_.x = f2b(s[nf][0]); pv_.y = f2b(s[nf][1]);
            pv_.z = f2b(s[nf][2]); pv_.w = f2b(s[nf][3]);
            *(ushort4*)((char*)&Ps[w][lane15][0] + SW(lane15, nf * 32 + lgrp * 8)) = pv_;
        }
        #pragma unroll
        for (int kk = 0; kk < 2; ++kk) {
            bf16x8 pa = *(const bf16x8*)((const char*)&Ps[w][lane15][0] +
                                         SW(lane15, kk * 64 + lgrp * 16));
            #pragma unroll
            for (int nf = 0; nf < 4; ++nf) {
                bf16x8 vb = *(const bf16x8*)((const char*)&Vs[jg][nf * 16 + lane15][0] +
                                             SW(lane15, kk * 64 + lgrp * 16));
                o[nf] = __builtin_amdgcn_mfma_f32_16x16x32_bf16(pa, vb, o[nf], 0, 0, 0);
            }
        }
    }

    // split-softmax merge (Ps dead; Oscr overlays it)
    __syncthreads();
    if (jg == 1) {
        if (lane < 16) { Mscr[g][lane] = m_run; Lscr[g][lane] = l_run; }
        #pragma unroll
        for (int nf = 0; nf < 4; ++nf)
            #pragma unroll
            for (int rr = 0; rr < 4; ++rr)
                Oscr[g][lgrp * 4 + rr][nf * 16 + lane15] = o[nf][rr];
    }
    __syncthreads();
    if (jg == 0) {
        #pragma unroll
        for (int rr = 0; rr < 4; ++rr) {
            int row = lgrp * 4 + rr;
            float m1 = __shfl(m_run, row);
            float l1 = __shfl(l_run, row);
            float m2 = Mscr[g][row];
            float l2 = Lscr[g][row];
            float mm = fmaxf(m1, m2);
            float e1 = __expf(m1 - mm), e2 = __expf(m2 - mm);
            float inv = 1.f / (l1 * e1 + l2 * e2);
            long grow = (long)b * 512 + i0 + g * 16 + row;
            #pragma unroll
            for (int nf = 0; nf < 4; ++nf) {
                int dh = nf * 16 + lane15;
                float o2 = Oscr[g][row][dh];
                float val = (o[nf][rr] * e1 + o2 * e2) * inv;
                float xgv = b2f(Xg[grow * 1024 + h * 64 + dh]);
                float gate = 1.f / (1.f + __expf(-xgv));
                Og[grow * 1024 + h * 64 + dh] = f2b(val * gate);
            }
        }
    }
}

// ---------------- output GEMM: out = Og @ w_o (M=1024,N=384,K=1024) ---------
__global__ __launch_bounds__(256) void k_out(const unsigned short* __restrict__ Og,
                                             const unsigned short* __restrict__ Wot,
                                             float* __restrict__ out) {
    __shared__ unsigned short As[64][64 + PAD];
    __shared__ unsigned short Bs[64][64 + PAD];
    int m0 = blockIdx.x * 64, n0 = blockIdx.y * 64;
    int t = threadIdx.x, wave = t >> 6, lane = t & 63;
    int wr = wave >> 1, wc = wave & 1;
    int lane15 = lane & 15, kg = lane >> 4;
    f32x4 acc[2][2] = {};
    for (int k0 = 0; k0 < 1024; k0 += 64) {
        __syncthreads();
        {
            int r = t >> 2, qd = t & 3;
            const uint4* s1 = (const uint4*)(Og + (long)(m0 + r) * 1024 + k0 + qd * 16);
            uint4* d1 = (uint4*)&As[r][qd * 16];
            d1[0] = s1[0]; d1[1] = s1[1];
            const uint4* s2 = (const uint4*)(Wot + (long)(n0 + r) * 1024 + k0 + qd * 16);
            uint4* d2 = (uint4*)&Bs[r][qd * 16];
            d2[0] = s2[0]; d2[1] = s2[1];
        }
        __syncthreads();
        #pragma unroll
        for (int ks = 0; ks < 2; ++ks) {
            bf16x8 a[2], bbv[2];
            #pragma unroll
            for (int mf = 0; mf < 2; ++mf)
                a[mf] = *(const bf16x8*)&As[wr * 32 + mf * 16 + lane15][ks * 32 + kg * 8];
            #pragma unroll
            for (int nf = 0; nf < 2; ++nf)
                bbv[nf] = *(const bf16x8*)&Bs[wc * 32 + nf * 16 + lane15][ks * 32 + kg * 8];
            #pragma unroll
            for (int mf = 0; mf < 2; ++mf)
                #pragma unroll
                for (int nf = 0; nf < 2; ++nf)
                    acc[mf][nf] = __builtin_amdgcn_mfma_f32_16x16x32_bf16(a[mf], bbv[nf], acc[mf][nf], 0, 0, 0);
        }
    }
    int lgrp = lane >> 4;
    #pragma unroll
    for (int mf = 0; mf < 2; ++mf) {
        #pragma unroll
        for (int nf = 0; nf < 2; ++nf) {
            int col = n0 + wc * 32 + nf * 16 + lane15;
            int row0 = m0 + wr * 32 + mf * 16 + lgrp * 4;
            #pragma unroll
            for (int rr = 0; rr < 4; ++rr)
                out[(long)(row0 + rr) * DS_ + col] = acc[mf][nf][rr];
        }
    }
}

extern "C" void kernel_launch(void* const* d_in, const int* in_sizes, int n_in,
                              void* d_out, int out_size, void* d_ws, size_t ws_size,
                              hipStream_t stream) {
    const float* single = (const float*)d_in[0];
    const float* pw     = (const float*)d_in[1];
    const float* gamma  = (const float*)d_in[2];
    const float* beta   = (const float*)d_in[3];
    const float* wb     = (const float*)d_in[4];
    const float* abb    = (const float*)d_in[5];
    const float* wq     = (const float*)d_in[6];
    const float* wk     = (const float*)d_in[7];
    const float* wv     = (const float*)d_in[8];
    const float* wg     = (const float*)d_in[9];
    const float* wo     = (const float*)d_in[10];
    float* out = (float*)d_out;
    char* ws = (char*)d_ws;

    unsigned short* SP  = (unsigned short*)(ws);                 // 16 MB bias [b][h][i][j]
    unsigned short* Qb  = (unsigned short*)(ws + 16777216);      // 2 MB (pre-scaled 0.125)
    unsigned short* Kb  = (unsigned short*)(ws + 18874368);      // 2 MB
    unsigned short* Vt  = (unsigned short*)(ws + 20971520);      // 2 MB [b][h][dh][n]
    unsigned short* Xg  = (unsigned short*)(ws + 23068672);      // 2 MB
    unsigned short* Og  = (unsigned short*)(ws + 25165824);      // 2 MB
    unsigned short* Wt  = (unsigned short*)(ws + 27262976);      // 3 MB [4*1024][384]
    unsigned short* Wot = (unsigned short*)(ws + 30408704);      // 0.75 MB [384][1024]

    k_pre<<<3968, 256, 0, stream>>>(pw, abb, gamma, beta, wb,
                                    wq, wk, wv, wg, wo, Wt, Wot, SP);
    k_proj<<<dim3(16, 32), 256, 0, stream>>>(single, Wt, Qb, Kb, Vt, Xg);
    k_flash<<<dim3(8, 32), 512, 0, stream>>>(Qb, Kb, Vt, SP, Xg, Og);
    k_out<<<dim3(16, 6), 256, 0, stream>>>(Og, Wot, out);
}

// Round 17
// 114.161 us; speedup vs baseline: 1.4567x; 1.4567x over previous
//
#include <hip/hip_runtime.h>
#include <hip/hip_bf16.h>

#define B_ 2
#define N_ 512
#define DS_ 384
#define DP_ 128
#define H_ 16
#define DH_ 64
#define DI_ 1024
#define MAXSEQ 2048
#define PAD 8

typedef float f32x4 __attribute__((ext_vector_type(4)));
typedef short bf16x8 __attribute__((ext_vector_type(8)));
typedef unsigned int u32x4 __attribute__((ext_vector_type(4)));

__device__ __forceinline__ unsigned short f2b(float f) {
    unsigned int u = __builtin_bit_cast(unsigned int, f);
    u += 0x7FFFu + ((u >> 16) & 1u);
    return (unsigned short)(u >> 16);
}
__device__ __forceinline__ float b2f(unsigned short s) {
    unsigned int u = ((unsigned int)s) << 16;
    return __builtin_bit_cast(float, u);
}

// XOR swizzle: byte-column ^ ((row&7)<<4). Applied on BOTH write and read.
#define SW(row, bc) ((bc) ^ (((row) & 7) << 4))

// ---- k_pre: bias blocks (bid<8192) + weight transposes (bid>=8192) ---------
// Bias v5 + NON-TEMPORAL pw stream (268MB read-once > 256MB L3; don't allocate).
// NOTE (R15 lesson): no register prefetch across barriers — the compiler's
// s_waitcnt vmcnt(0) before s_barrier drains it; rely on inter-block overlap.
__global__ __launch_bounds__(256) void k_pre(const float* __restrict__ pw,
                                             const float* __restrict__ abb,
                                             const float* __restrict__ gamma,
                                             const float* __restrict__ beta,
                                             const float* __restrict__ wb,
                                             const float* __restrict__ wq,
                                             const float* __restrict__ wk,
                                             const float* __restrict__ wv,
                                             const float* __restrict__ wg,
                                             const float* __restrict__ wo,
                                             unsigned short* __restrict__ Wt,
                                             unsigned short* __restrict__ Wot,
                                             unsigned short* __restrict__ biasP) {
    __shared__ float Xs[64 * 128];                          // 32 KB (also transpose tile)
    __shared__ float rsum[4][16] __attribute__((aligned(16)));
    __shared__ float rsq[4][16] __attribute__((aligned(16)));
    int bid = blockIdx.x;
    int t = threadIdx.x;

    if (bid >= 8192) {                  // ---- transpose path ----
        int tid = bid - 8192;
        int z = tid / 384, r = tid % 384;
        const float* in; unsigned short* out; int C, Rr, c0, r0;
        if (z < 4) {
            in = (z == 0) ? wq : (z == 1) ? wk : (z == 2) ? wv : wg;
            out = Wt + (long)z * 1024 * 384;
            C = 1024; Rr = 384;
            c0 = (r & 31) * 32; r0 = (r >> 5) * 32;
        } else {
            in = wo; out = Wot; C = 384; Rr = 1024;
            c0 = (r % 12) * 32; r0 = (r / 12) * 32;
        }
        float (*tile)[33] = (float(*)[33])Xs;
        int tx = t & 31, ty = t >> 5;
        #pragma unroll
        for (int i = ty; i < 32; i += 8)
            tile[i][tx] = in[(long)(r0 + i) * C + (c0 + tx)];
        __syncthreads();
        #pragma unroll
        for (int i = ty; i < 32; i += 8)
            out[(long)(c0 + i) * Rr + (r0 + tx)] = f2b(tile[tx][i]);
        return;
    }

    // ---- bias path ----
    int w = t >> 6, lane = t & 63;
    int lane15 = lane & 15, kg = lane >> 4;
    long p0 = (long)bid * 64;                   // first (b,i,j)-flat row
    int i_blk = (int)((p0 >> 9) & (N_ - 1));
    int j0 = (int)(p0 & (N_ - 1));
    long bb = p0 >> 18;

    // stage: linear 1KB-per-wave-instr NT global reads, XOR-swizzled LDS writes
    const char* src = (const char*)(pw + (p0 << 7));
    char* lds = (char*)Xs;
    #pragma unroll
    for (int c = 0; c < 8; ++c) {
        int L = c * 4096 + t * 16;
        int row = L >> 9, b = L & 511;
        u32x4 v = __builtin_nontemporal_load((const u32x4*)(src + L));
        *(u32x4*)(lds + (row << 9) + (b ^ ((row & 7) << 4))) = v;
    }

    // inline prep (L2-hot 8KB wb): gb[kk] + sh/th partials, shuffle-reduced
    float shp = 0.f, thp = 0.f;
    bf16x8 gb[4];
    #pragma unroll
    for (int kk = 0; kk < 4; ++kk) {
        bf16x8 a;
        unsigned short* ap = (unsigned short*)&a;
        #pragma unroll
        for (int e = 0; e < 8; ++e) {
            int d = kk * 32 + kg * 8 + e;
            float wv_ = wb[d * 16 + lane15];
            float gv = gamma[d];
            ap[e] = f2b(gv * wv_);
            shp = fmaf(gv, wv_, shp);
            thp = fmaf(beta[d], wv_, thp);
        }
        gb[kk] = a;
    }
    shp += __shfl_xor(shp, 16); shp += __shfl_xor(shp, 32);
    thp += __shfl_xor(thp, 16); thp += __shfl_xor(thp, 32);
    float sh = shp, th = thp;
    __syncthreads();

    // fragments: row = w*16 + lane15, swizzled read
    int row = w * 16 + lane15;
    const char* rbase = lds + (row << 9);
    int sw = (lane15 & 7) << 4;
    f32x4 xa[4], xb4[4];
    #pragma unroll
    for (int kk = 0; kk < 4; ++kk) {
        int b0 = kk * 128 + kg * 32;
        xa[kk]  = *(const f32x4*)(rbase + ((b0) ^ sw));
        xb4[kk] = *(const f32x4*)(rbase + ((b0 + 16) ^ sw));
    }
    float s = 0.f, q = 0.f;
    #pragma unroll
    for (int kk = 0; kk < 4; ++kk) {
        s += xa[kk][0] + xa[kk][1] + xa[kk][2] + xa[kk][3];
        s += xb4[kk][0] + xb4[kk][1] + xb4[kk][2] + xb4[kk][3];
        #pragma unroll
        for (int e = 0; e < 4; ++e) {
            q = fmaf(xa[kk][e], xa[kk][e], q);
            q = fmaf(xb4[kk][e], xb4[kk][e], q);
        }
    }
    s += __shfl_xor(s, 16); s += __shfl_xor(s, 32);
    q += __shfl_xor(q, 16); q += __shfl_xor(q, 32);
    if (lane < 16) { rsum[w][lane15] = s; rsq[w][lane15] = q; }

    f32x4 acc = {};
    #pragma unroll
    for (int kk = 0; kk < 4; ++kk) {
        bf16x8 a;
        unsigned short* ap = (unsigned short*)&a;
        ap[0] = f2b(xa[kk][0]);  ap[1] = f2b(xa[kk][1]);
        ap[2] = f2b(xa[kk][2]);  ap[3] = f2b(xa[kk][3]);
        ap[4] = f2b(xb4[kk][0]); ap[5] = f2b(xb4[kk][1]);
        ap[6] = f2b(xb4[kk][2]); ap[7] = f2b(xb4[kk][3]);
        acc = __builtin_amdgcn_mfma_f32_16x16x32_bf16(a, gb[kk], acc, 0, 0, 0);
    }
    int jr = w * 16 + kg * 4;
    float4 rs = *(const float4*)&rsum[w][kg * 4];
    float4 rq = *(const float4*)&rsq[w][kg * 4];
    float4 av = *(const float4*)(abb + (long)i_blk * MAXSEQ + j0 + jr);
    unsigned short* planeBase = biasP + ((bb * H_ + lane15) * N_ + i_blk) * N_ + j0;
    ushort4 res;
    float mu, var;
    mu = rs.x * (1.f / DP_); var = fmaf(rq.x, 1.f / DP_, -mu * mu);
    res.x = f2b(fmaf(rsqrtf(var + 1e-5f), acc[0] - mu * sh, th + av.x));
    mu = rs.y * (1.f / DP_); var = fmaf(rq.y, 1.f / DP_, -mu * mu);
    res.y = f2b(fmaf(rsqrtf(var + 1e-5f), acc[1] - mu * sh, th + av.y));
    mu = rs.z * (1.f / DP_); var = fmaf(rq.z, 1.f / DP_, -mu * mu);
    res.z = f2b(fmaf(rsqrtf(var + 1e-5f), acc[2] - mu * sh, th + av.z));
    mu = rs.w * (1.f / DP_); var = fmaf(rq.w, 1.f / DP_, -mu * mu);
    res.w = f2b(fmaf(rsqrtf(var + 1e-5f), acc[3] - mu * sh, th + av.w));
    *(ushort4*)(planeBase + jr) = res;
}

// ---------------- QKVG projection GEMM (M=1024, N=4096, K=384) --------------
// 64x128 tiles, 512 blocks (2/CU). Q pre-scaled by 0.125.
__global__ __launch_bounds__(256) void k_proj(const float* __restrict__ X,
                                              const unsigned short* __restrict__ Wt,
                                              unsigned short* __restrict__ Qb,
                                              unsigned short* __restrict__ Kb,
                                              unsigned short* __restrict__ Vt,
                                              unsigned short* __restrict__ Xg) {
    __shared__ unsigned short As[64][64 + PAD];
    __shared__ unsigned short Bs[128][64 + PAD];
    int m0 = blockIdx.x * 64;
    int n0 = blockIdx.y * 128;
    int t = threadIdx.x;
    int wave = t >> 6, lane = t & 63;
    int wr = wave >> 1, wc = wave & 1;
    int lane15 = lane & 15, kg = lane >> 4;
    int rA = t >> 2, qA = t & 3;
    int rB = t >> 1, hB = t & 1;
    f32x4 acc[2][4] = {};
    for (int k0 = 0; k0 < DS_; k0 += 64) {
        __syncthreads();
        {
            const float4* srcA = (const float4*)(X + (long)(m0 + rA) * DS_ + k0 + qA * 16);
            unsigned short* dstA = &As[rA][qA * 16];
            #pragma unroll
            for (int ii = 0; ii < 4; ++ii) {
                float4 v = srcA[ii];
                dstA[ii * 4 + 0] = f2b(v.x); dstA[ii * 4 + 1] = f2b(v.y);
                dstA[ii * 4 + 2] = f2b(v.z); dstA[ii * 4 + 3] = f2b(v.w);
            }
            const uint4* srcB = (const uint4*)(Wt + (long)(n0 + rB) * DS_ + k0 + hB * 32);
            uint4* dstB = (uint4*)&Bs[rB][hB * 32];
            dstB[0] = srcB[0]; dstB[1] = srcB[1]; dstB[2] = srcB[2]; dstB[3] = srcB[3];
        }
        __syncthreads();
        #pragma unroll
        for (int ks = 0; ks < 2; ++ks) {
            bf16x8 a[2], bbv[4];
            #pragma unroll
            for (int mf = 0; mf < 2; ++mf)
                a[mf] = *(const bf16x8*)&As[wr * 32 + mf * 16 + lane15][ks * 32 + kg * 8];
            #pragma unroll
            for (int nf = 0; nf < 4; ++nf)
                bbv[nf] = *(const bf16x8*)&Bs[wc * 64 + nf * 16 + lane15][ks * 32 + kg * 8];
            #pragma unroll
            for (int mf = 0; mf < 2; ++mf)
                #pragma unroll
                for (int nf = 0; nf < 4; ++nf)
                    acc[mf][nf] = __builtin_amdgcn_mfma_f32_16x16x32_bf16(a[mf], bbv[nf], acc[mf][nf], 0, 0, 0);
        }
    }
    int p = n0 >> 10;
    int lgrp = lane >> 4;
    #pragma unroll
    for (int mf = 0; mf < 2; ++mf) {
        #pragma unroll
        for (int nf = 0; nf < 4; ++nf) {
            int col = n0 + wc * 64 + nf * 16 + lane15;
            int ch = col & 1023;
            int h = ch >> 6, dh = ch & 63;
            int row0 = m0 + wr * 32 + mf * 16 + lgrp * 4;
            if (p == 0 || p == 1) {
                unsigned short* base = (p == 0) ? Qb : Kb;
                float scl = (p == 0) ? 0.125f : 1.0f;
                #pragma unroll
                for (int rr = 0; rr < 4; ++rr) {
                    int rowx = row0 + rr;
                    int b = rowx >> 9, n = rowx & 511;
                    base[(((long)(b * 16 + h)) * 512 + n) * 64 + dh] = f2b(acc[mf][nf][rr] * scl);
                }
            } else if (p == 2) {
                int b = row0 >> 9, n = row0 & 511;
                ushort4 v;
                v.x = f2b(acc[mf][nf][0]); v.y = f2b(acc[mf][nf][1]);
                v.z = f2b(acc[mf][nf][2]); v.w = f2b(acc[mf][nf][3]);
                *(ushort4*)&Vt[(((long)(b * 16 + h)) * 64 + dh) * 512 + n] = v;
            } else {
                #pragma unroll
                for (int rr = 0; rr < 4; ++rr) {
                    int rowx = row0 + rr;
                    Xg[(long)rowx * 1024 + ch] = f2b(acc[mf][nf][rr]);
                }
            }
        }
    }
}

// ---------------- fused flash attention -------------------------------------
// v4: pad-free XOR-swizzled LDS + Ps/Oscr union -> 64.5 KB -> 2 blocks/CU.
__global__ __launch_bounds__(512) void k_flash(const unsigned short* __restrict__ Qb,
                                               const unsigned short* __restrict__ Kb,
                                               const unsigned short* __restrict__ Vt,
                                               const unsigned short* __restrict__ biasP,
                                               const unsigned short* __restrict__ Xg,
                                               unsigned short* __restrict__ Og) {
    __shared__ unsigned short Kt[2][64][64];   // 16 KB, swizzled
    __shared__ unsigned short Vs[2][64][64];   // 16 KB, swizzled
    __shared__ unsigned short Bt[2][64][64];   // 16 KB, swizzled
    __shared__ char PsOscr[16384];             // Ps (main loop) ∪ Oscr (merge)
    __shared__ float Mscr[4][16], Lscr[4][16];
    unsigned short (*Ps)[16][64] = (unsigned short(*)[16][64])PsOscr;
    float (*Oscr)[16][64] = (float(*)[16][64])PsOscr;
    int bh = blockIdx.y;
    int b = bh >> 4, h = bh & 15;
    int i0 = blockIdx.x * 64;
    int t = threadIdx.x, w = t >> 6, lane = t & 63;
    int g = w & 3, jg = w >> 2;
    int lane15 = lane & 15, lgrp = lane >> 4;
    int tl = t & 255;
    int rs_ = tl >> 3, cs_ = tl & 7;

    bf16x8 qf[2];
    #pragma unroll
    for (int kk = 0; kk < 2; ++kk)
        qf[kk] = *(const bf16x8*)&Qb[((long)bh * 512 + i0 + g * 16 + lane15) * 64 + kk * 32 + lgrp * 8];

    float m_run = -1e30f, l_run = 0.f;
    f32x4 o[4] = {};

    for (int jtl = 0; jtl < 4; ++jtl) {
        int j0 = (jg * 4 + jtl) * 64;
        __syncthreads();
        {
            int r2 = rs_ + 32;
            *(uint4*)((char*)&Kt[jg][rs_][0] + SW(rs_, cs_ * 16)) =
                *(const uint4*)&Kb[((long)bh * 512 + j0 + rs_) * 64 + cs_ * 8];
            *(uint4*)((char*)&Vs[jg][rs_][0] + SW(rs_, cs_ * 16)) =
                *(const uint4*)&Vt[((long)bh * 64 + rs_) * 512 + j0 + cs_ * 8];
            *(uint4*)((char*)&Bt[jg][rs_][0] + SW(rs_, cs_ * 16)) =
                *(const uint4*)&biasP[((long)bh * 512 + i0 + rs_) * 512 + j0 + cs_ * 8];
            *(uint4*)((char*)&Kt[jg][r2][0] + SW(r2, cs_ * 16)) =
                *(const uint4*)&Kb[((long)bh * 512 + j0 + r2) * 64 + cs_ * 8];
            *(uint4*)((char*)&Vs[jg][r2][0] + SW(r2, cs_ * 16)) =
                *(const uint4*)&Vt[((long)bh * 64 + r2) * 512 + j0 + cs_ * 8];
            *(uint4*)((char*)&Bt[jg][r2][0] + SW(r2, cs_ * 16)) =
                *(const uint4*)&biasP[((long)bh * 512 + i0 + r2) * 512 + j0 + cs_ * 8];
        }
        __syncthreads();

        f32x4 s[4];
        #pragma unroll
        for (int nf = 0; nf < 4; ++nf) {
            f32x4 z = {};
            #pragma unroll
            for (int kk = 0; kk < 2; ++kk) {
                bf16x8 af = *(const bf16x8*)((const char*)&Kt[jg][nf * 16 + lane15][0] +
                                             SW(lane15, kk * 64 + lgrp * 16));
                z = __builtin_amdgcn_mfma_f32_16x16x32_bf16(af, qf[kk], z, 0, 0, 0);
            }
            s[nf] = z;
        }
        #pragma unroll
        for (int nf = 0; nf < 4; ++nf) {
            ushort4 bv = *(const ushort4*)((const char*)&Bt[jg][g * 16 + lane15][0] +
                                           SW(lane15, nf * 32 + lgrp * 8));
            s[nf][0] += b2f(bv.x); s[nf][1] += b2f(bv.y);
            s[nf][2] += b2f(bv.z); s[nf][3] += b2f(bv.w);
        }

        float pmax = s[0][0];
        #pragma unroll
        for (int nf = 0; nf < 4; ++nf)
            #pragma unroll
            for (int rr = 0; rr < 4; ++rr) pmax = fmaxf(pmax, s[nf][rr]);
        pmax = fmaxf(pmax, __shfl_xor(pmax, 16));
        pmax = fmaxf(pmax, __shfl_xor(pmax, 32));
        float m_new = fmaxf(m_run, pmax);
        float scale = __expf(m_run - m_new);
        float psum = 0.f;
        #pragma unroll
        for (int nf = 0; nf < 4; ++nf)
            #pragma unroll
            for (int rr = 0; rr < 4; ++rr) {
                s[nf][rr] = __expf(s[nf][rr] - m_new);
                psum += s[nf][rr];
            }
        psum += __shfl_xor(psum, 16);
        psum += __shfl_xor(psum, 32);
        l_run = l_run * scale + psum;
        m_run = m_new;
        #pragma unroll
        for (int rr = 0; rr < 4; ++rr) {
            float sc = __shfl(scale, lgrp * 4 + rr);
            #pragma unroll
            for (int nf = 0; nf < 4; ++nf) o[nf][rr] *= sc;
        }
        #pragma unroll
        for (int nf = 0; nf < 4; ++nf) {
            ushort4 pv_;
            pv_.x = f2b(s[nf][0]); pv_.y = f2b(s[nf][1]);
            pv_.z = f2b(s[nf][2]); pv_.w = f2b(s[nf][3]);
            *(ushort4*)((char*)&Ps[w][lane15][0] + SW(lane15, nf * 32 + lgrp * 8)) = pv_;
        }
        #pragma unroll
        for (int kk = 0; kk < 2; ++kk) {
            bf16x8 pa = *(const bf16x8*)((const char*)&Ps[w][lane15][0] +
                                         SW(lane15, kk * 64 + lgrp * 16));
            #pragma unroll
            for (int nf = 0; nf < 4; ++nf) {
                bf16x8 vb = *(const bf16x8*)((const char*)&Vs[jg][nf * 16 + lane15][0] +
                                             SW(lane15, kk * 64 + lgrp * 16));
                o[nf] = __builtin_amdgcn_mfma_f32_16x16x32_bf16(pa, vb, o[nf], 0, 0, 0);
            }
        }
    }

    // split-softmax merge (Ps dead; Oscr overlays it)
    __syncthreads();
    if (jg == 1) {
        if (lane < 16) { Mscr[g][lane] = m_run; Lscr[g][lane] = l_run; }
        #pragma unroll
        for (int nf = 0; nf < 4; ++nf)
            #pragma unroll
            for (int rr = 0; rr < 4; ++rr)
                Oscr[g][lgrp * 4 + rr][nf * 16 + lane15] = o[nf][rr];
    }
    __syncthreads();
    if (jg == 0) {
        #pragma unroll
        for (int rr = 0; rr < 4; ++rr) {
            int row = lgrp * 4 + rr;
            float m1 = __shfl(m_run, row);
            float l1 = __shfl(l_run, row);
            float m2 = Mscr[g][row];
            float l2 = Lscr[g][row];
            float mm = fmaxf(m1, m2);
            float e1 = __expf(m1 - mm), e2 = __expf(m2 - mm);
            float inv = 1.f / (l1 * e1 + l2 * e2);
            long grow = (long)b * 512 + i0 + g * 16 + row;
            #pragma unroll
            for (int nf = 0; nf < 4; ++nf) {
                int dh = nf * 16 + lane15;
                float o2 = Oscr[g][row][dh];
                float val = (o[nf][rr] * e1 + o2 * e2) * inv;
                float xgv = b2f(Xg[grow * 1024 + h * 64 + dh]);
                float gate = 1.f / (1.f + __expf(-xgv));
                Og[grow * 1024 + h * 64 + dh] = f2b(val * gate);
            }
        }
    }
}

// ---------------- output GEMM: out = Og @ w_o (M=1024,N=384,K=1024) ---------
__global__ __launch_bounds__(256) void k_out(const unsigned short* __restrict__ Og,
                                             const unsigned short* __restrict__ Wot,
                                             float* __restrict__ out) {
    __shared__ unsigned short As[64][64 + PAD];
    __shared__ unsigned short Bs[64][64 + PAD];
    int m0 = blockIdx.x * 64, n0 = blockIdx.y * 64;
    int t = threadIdx.x, wave = t >> 6, lane = t & 63;
    int wr = wave >> 1, wc = wave & 1;
    int lane15 = lane & 15, kg = lane >> 4;
    f32x4 acc[2][2] = {};
    for (int k0 = 0; k0 < 1024; k0 += 64) {
        __syncthreads();
        {
            int r = t >> 2, qd = t & 3;
            const uint4* s1 = (const uint4*)(Og + (long)(m0 + r) * 1024 + k0 + qd * 16);
            uint4* d1 = (uint4*)&As[r][qd * 16];
            d1[0] = s1[0]; d1[1] = s1[1];
            const uint4* s2 = (const uint4*)(Wot + (long)(n0 + r) * 1024 + k0 + qd * 16);
            uint4* d2 = (uint4*)&Bs[r][qd * 16];
            d2[0] = s2[0]; d2[1] = s2[1];
        }
        __syncthreads();
        #pragma unroll
        for (int ks = 0; ks < 2; ++ks) {
            bf16x8 a[2], bbv[2];
            #pragma unroll
            for (int mf = 0; mf < 2; ++mf)
                a[mf] = *(const bf16x8*)&As[wr * 32 + mf * 16 + lane15][ks * 32 + kg * 8];
            #pragma unroll
            for (int nf = 0; nf < 2; ++nf)
                bbv[nf] = *(const bf16x8*)&Bs[wc * 32 + nf * 16 + lane15][ks * 32 + kg * 8];
            #pragma unroll
            for (int mf = 0; mf < 2; ++mf)
                #pragma unroll
                for (int nf = 0; nf < 2; ++nf)
                    acc[mf][nf] = __builtin_amdgcn_mfma_f32_16x16x32_bf16(a[mf], bbv[nf], acc[mf][nf], 0, 0, 0);
        }
    }
    int lgrp = lane >> 4;
    #pragma unroll
    for (int mf = 0; mf < 2; ++mf) {
        #pragma unroll
        for (int nf = 0; nf < 2; ++nf) {
            int col = n0 + wc * 32 + nf * 16 + lane15;
            int row0 = m0 + wr * 32 + mf * 16 + lgrp * 4;
            #pragma unroll
            for (int rr = 0; rr < 4; ++rr)
                out[(long)(row0 + rr) * DS_ + col] = acc[mf][nf][rr];
        }
    }
}

extern "C" void kernel_launch(void* const* d_in, const int* in_sizes, int n_in,
                              void* d_out, int out_size, void* d_ws, size_t ws_size,
                              hipStream_t stream) {
    const float* single = (const float*)d_in[0];
    const float* pw     = (const float*)d_in[1];
    const float* gamma  = (const float*)d_in[2];
    const float* beta   = (const float*)d_in[3];
    const float* wb     = (const float*)d_in[4];
    const float* abb    = (const float*)d_in[5];
    const float* wq     = (const float*)d_in[6];
    const float* wk     = (const float*)d_in[7];
    const float* wv     = (const float*)d_in[8];
    const float* wg     = (const float*)d_in[9];
    const float* wo     = (const float*)d_in[10];
    float* out = (float*)d_out;
    char* ws = (char*)d_ws;

    unsigned short* SP  = (unsigned short*)(ws);                 // 16 MB bias [b][h][i][j]
    unsigned short* Qb  = (unsigned short*)(ws + 16777216);      // 2 MB (pre-scaled 0.125)
    unsigned short* Kb  = (unsigned short*)(ws + 18874368);      // 2 MB
    unsigned short* Vt  = (unsigned short*)(ws + 20971520);      // 2 MB [b][h][dh][n]
    unsigned short* Xg  = (unsigned short*)(ws + 23068672);      // 2 MB
    unsigned short* Og  = (unsigned short*)(ws + 25165824);      // 2 MB
    unsigned short* Wt  = (unsigned short*)(ws + 27262976);      // 3 MB [4*1024][384]
    unsigned short* Wot = (unsigned short*)(ws + 30408704);      // 0.75 MB [384][1024]

    k_pre<<<10112, 256, 0, stream>>>(pw, abb, gamma, beta, wb,
                                     wq, wk, wv, wg, wo, Wt, Wot, SP);
    k_proj<<<dim3(16, 32), 256, 0, stream>>>(single, Wt, Qb, Kb, Vt, Xg);
    k_flash<<<dim3(8, 32), 512, 0, stream>>>(Qb, Kb, Vt, SP, Xg, Og);
    k_out<<<dim3(16, 6), 256, 0, stream>>>(Og, Wot, out);
}

// Round 18
// 112.831 us; speedup vs baseline: 1.4738x; 1.0118x over previous
//
#include <hip/hip_runtime.h>
#include <hip/hip_bf16.h>

#define B_ 2
#define N_ 512
#define DS_ 384
#define DP_ 128
#define H_ 16
#define DH_ 64
#define DI_ 1024
#define MAXSEQ 2048
#define PAD 8

typedef float f32x4 __attribute__((ext_vector_type(4)));
typedef short bf16x8 __attribute__((ext_vector_type(8)));
typedef unsigned int u32x4 __attribute__((ext_vector_type(4)));

__device__ __forceinline__ unsigned short f2b(float f) {
    unsigned int u = __builtin_bit_cast(unsigned int, f);
    u += 0x7FFFu + ((u >> 16) & 1u);
    return (unsigned short)(u >> 16);
}
__device__ __forceinline__ float b2f(unsigned short s) {
    unsigned int u = ((unsigned int)s) << 16;
    return __builtin_bit_cast(float, u);
}

// XOR swizzle: byte-column ^ ((row&7)<<4). Applied on BOTH write and read.
#define SW(row, bc) ((bc) ^ (((row) & 7) << 4))

// ---- k_pre: bias wave-streams (bid<1024) + weight transposes (bid>=1024) ---
// Bias v8: BARRIER-FREE per-wave pipeline. Each of the 4 waves owns a private
// 8KB LDS tile and grid-strides 8 x 16-row tiles:
//   ds_write(s) -> prefetch NT global(s+1) -> ds_read/compute(s)
// No __syncthreads in the bias path => no vmcnt(0) drain => next-tile loads
// stay in flight through compute (the R15 prefetch, minus the barrier).
__global__ __launch_bounds__(256) void k_pre(const float* __restrict__ pw,
                                             const float* __restrict__ abb,
                                             const float* __restrict__ gamma,
                                             const float* __restrict__ beta,
                                             const float* __restrict__ wb,
                                             const float* __restrict__ wq,
                                             const float* __restrict__ wk,
                                             const float* __restrict__ wv,
                                             const float* __restrict__ wg,
                                             const float* __restrict__ wo,
                                             unsigned short* __restrict__ Wt,
                                             unsigned short* __restrict__ Wot,
                                             unsigned short* __restrict__ biasP) {
    __shared__ float Xs4[4][16 * 128];          // 4 x 8KB private wave tiles
    __shared__ float rsum4[4][16] __attribute__((aligned(16)));
    __shared__ float rsq4[4][16] __attribute__((aligned(16)));
    int bid = blockIdx.x;
    int t = threadIdx.x;

    if (bid >= 1024) {                  // ---- transpose path ----
        int tid = bid - 1024;
        int z = tid / 384, r = tid % 384;
        const float* in; unsigned short* out; int C, Rr, c0, r0;
        if (z < 4) {
            in = (z == 0) ? wq : (z == 1) ? wk : (z == 2) ? wv : wg;
            out = Wt + (long)z * 1024 * 384;
            C = 1024; Rr = 384;
            c0 = (r & 31) * 32; r0 = (r >> 5) * 32;
        } else {
            in = wo; out = Wot; C = 384; Rr = 1024;
            c0 = (r % 12) * 32; r0 = (r / 12) * 32;
        }
        float (*tile)[33] = (float(*)[33])&Xs4[0][0];
        int tx = t & 31, ty = t >> 5;
        #pragma unroll
        for (int i = ty; i < 32; i += 8)
            tile[i][tx] = in[(long)(r0 + i) * C + (c0 + tx)];
        __syncthreads();
        #pragma unroll
        for (int i = ty; i < 32; i += 8)
            out[(long)(c0 + i) * Rr + (r0 + tx)] = f2b(tile[tx][i]);
        return;
    }

    // ---- bias path (no __syncthreads below this point) ----
    int w = t >> 6, lane = t & 63;
    int lane15 = lane & 15, kg = lane >> 4;

    // per-wave prep (L2-hot 8KB wb): gb[kk] + sh/th, shuffle-reduced
    float shp = 0.f, thp = 0.f;
    bf16x8 gb[4];
    #pragma unroll
    for (int kk = 0; kk < 4; ++kk) {
        bf16x8 a;
        unsigned short* ap = (unsigned short*)&a;
        #pragma unroll
        for (int e = 0; e < 8; ++e) {
            int d = kk * 32 + kg * 8 + e;
            float wv_ = wb[d * 16 + lane15];
            float gv = gamma[d];
            ap[e] = f2b(gv * wv_);
            shp = fmaf(gv, wv_, shp);
            thp = fmaf(beta[d], wv_, thp);
        }
        gb[kk] = a;
    }
    shp += __shfl_xor(shp, 16); shp += __shfl_xor(shp, 32);
    thp += __shfl_xor(thp, 16); thp += __shfl_xor(thp, 32);
    float sh = shp, th = thp;

    char* lds = (char*)&Xs4[w][0];              // private 8KB region
    float* rsum = rsum4[w];
    float* rsq  = rsq4[w];
    long wstream = (long)bid * 4 + w;           // 0..4095 wave-streams

    // preload tile 0 (NT: 268MB stream-once, don't allocate in caches)
    u32x4 rg[8];
    {
        const char* src0 = (const char*)pw + (wstream << 13);
        #pragma unroll
        for (int c = 0; c < 8; ++c)
            rg[c] = __builtin_nontemporal_load((const u32x4*)(src0 + c * 1024 + lane * 16));
    }

    for (int s = 0; s < 8; ++s) {
        long tile = wstream + (long)s * 4096;
        long p0 = tile * 16;                    // first flat row of this tile
        int i_blk = (int)((p0 >> 9) & (N_ - 1));
        int j0 = (int)(p0 & (N_ - 1));
        long bb = p0 >> 18;

        // stage to private LDS (swizzled); per-wave LDS is in-order, no barrier
        #pragma unroll
        for (int c = 0; c < 8; ++c) {
            int L = c * 1024 + lane * 16;
            int row = L >> 9, b = L & 511;
            *(u32x4*)(lds + (row << 9) + (b ^ ((row & 7) << 4))) = rg[c];
        }
        // issue next tile's loads NOW — they stay in flight through compute
        if (s < 7) {
            const char* srcn = (const char*)pw + ((tile + 4096) << 13);
            #pragma unroll
            for (int c = 0; c < 8; ++c)
                rg[c] = __builtin_nontemporal_load((const u32x4*)(srcn + c * 1024 + lane * 16));
        }

        // fragments: row = lane15, swizzled read
        const char* rbase = lds + (lane15 << 9);
        int sw = (lane15 & 7) << 4;
        f32x4 xa[4], xb4[4];
        #pragma unroll
        for (int kk = 0; kk < 4; ++kk) {
            int b0 = kk * 128 + kg * 32;
            xa[kk]  = *(const f32x4*)(rbase + ((b0) ^ sw));
            xb4[kk] = *(const f32x4*)(rbase + ((b0 + 16) ^ sw));
        }
        float s_ = 0.f, q = 0.f;
        #pragma unroll
        for (int kk = 0; kk < 4; ++kk) {
            s_ += xa[kk][0] + xa[kk][1] + xa[kk][2] + xa[kk][3];
            s_ += xb4[kk][0] + xb4[kk][1] + xb4[kk][2] + xb4[kk][3];
            #pragma unroll
            for (int e = 0; e < 4; ++e) {
                q = fmaf(xa[kk][e], xa[kk][e], q);
                q = fmaf(xb4[kk][e], xb4[kk][e], q);
            }
        }
        s_ += __shfl_xor(s_, 16); s_ += __shfl_xor(s_, 32);
        q  += __shfl_xor(q, 16);  q  += __shfl_xor(q, 32);
        if (lane < 16) { rsum[lane15] = s_; rsq[lane15] = q; }

        f32x4 acc = {};
        #pragma unroll
        for (int kk = 0; kk < 4; ++kk) {
            bf16x8 a;
            unsigned short* ap = (unsigned short*)&a;
            ap[0] = f2b(xa[kk][0]);  ap[1] = f2b(xa[kk][1]);
            ap[2] = f2b(xa[kk][2]);  ap[3] = f2b(xa[kk][3]);
            ap[4] = f2b(xb4[kk][0]); ap[5] = f2b(xb4[kk][1]);
            ap[6] = f2b(xb4[kk][2]); ap[7] = f2b(xb4[kk][3]);
            acc = __builtin_amdgcn_mfma_f32_16x16x32_bf16(a, gb[kk], acc, 0, 0, 0);
        }
        // epilogue: lane holds col h=lane15, tile-rows kg*4 + rr
        int jr = kg * 4;
        float4 rs = *(const float4*)&rsum[jr];
        float4 rq = *(const float4*)&rsq[jr];
        float4 av = *(const float4*)(abb + (long)i_blk * MAXSEQ + j0 + jr);
        unsigned short* planeBase = biasP + ((bb * H_ + lane15) * N_ + i_blk) * N_ + j0;
        ushort4 res;
        float mu, var;
        mu = rs.x * (1.f / DP_); var = fmaf(rq.x, 1.f / DP_, -mu * mu);
        res.x = f2b(fmaf(rsqrtf(var + 1e-5f), acc[0] - mu * sh, th + av.x));
        mu = rs.y * (1.f / DP_); var = fmaf(rq.y, 1.f / DP_, -mu * mu);
        res.y = f2b(fmaf(rsqrtf(var + 1e-5f), acc[1] - mu * sh, th + av.y));
        mu = rs.z * (1.f / DP_); var = fmaf(rq.z, 1.f / DP_, -mu * mu);
        res.z = f2b(fmaf(rsqrtf(var + 1e-5f), acc[2] - mu * sh, th + av.z));
        mu = rs.w * (1.f / DP_); var = fmaf(rq.w, 1.f / DP_, -mu * mu);
        res.w = f2b(fmaf(rsqrtf(var + 1e-5f), acc[3] - mu * sh, th + av.w));
        *(ushort4*)(planeBase + jr) = res;
    }
}

// ---------------- QKVG projection GEMM (M=1024, N=4096, K=384) --------------
// 64x128 tiles, 512 blocks (2/CU). Q pre-scaled by 0.125.
__global__ __launch_bounds__(256) void k_proj(const float* __restrict__ X,
                                              const unsigned short* __restrict__ Wt,
                                              unsigned short* __restrict__ Qb,
                                              unsigned short* __restrict__ Kb,
                                              unsigned short* __restrict__ Vt,
                                              unsigned short* __restrict__ Xg) {
    __shared__ unsigned short As[64][64 + PAD];
    __shared__ unsigned short Bs[128][64 + PAD];
    int m0 = blockIdx.x * 64;
    int n0 = blockIdx.y * 128;
    int t = threadIdx.x;
    int wave = t >> 6, lane = t & 63;
    int wr = wave >> 1, wc = wave & 1;
    int lane15 = lane & 15, kg = lane >> 4;
    int rA = t >> 2, qA = t & 3;
    int rB = t >> 1, hB = t & 1;
    f32x4 acc[2][4] = {};
    for (int k0 = 0; k0 < DS_; k0 += 64) {
        __syncthreads();
        {
            const float4* srcA = (const float4*)(X + (long)(m0 + rA) * DS_ + k0 + qA * 16);
            unsigned short* dstA = &As[rA][qA * 16];
            #pragma unroll
            for (int ii = 0; ii < 4; ++ii) {
                float4 v = srcA[ii];
                dstA[ii * 4 + 0] = f2b(v.x); dstA[ii * 4 + 1] = f2b(v.y);
                dstA[ii * 4 + 2] = f2b(v.z); dstA[ii * 4 + 3] = f2b(v.w);
            }
            const uint4* srcB = (const uint4*)(Wt + (long)(n0 + rB) * DS_ + k0 + hB * 32);
            uint4* dstB = (uint4*)&Bs[rB][hB * 32];
            dstB[0] = srcB[0]; dstB[1] = srcB[1]; dstB[2] = srcB[2]; dstB[3] = srcB[3];
        }
        __syncthreads();
        #pragma unroll
        for (int ks = 0; ks < 2; ++ks) {
            bf16x8 a[2], bbv[4];
            #pragma unroll
            for (int mf = 0; mf < 2; ++mf)
                a[mf] = *(const bf16x8*)&As[wr * 32 + mf * 16 + lane15][ks * 32 + kg * 8];
            #pragma unroll
            for (int nf = 0; nf < 4; ++nf)
                bbv[nf] = *(const bf16x8*)&Bs[wc * 64 + nf * 16 + lane15][ks * 32 + kg * 8];
            #pragma unroll
            for (int mf = 0; mf < 2; ++mf)
                #pragma unroll
                for (int nf = 0; nf < 4; ++nf)
                    acc[mf][nf] = __builtin_amdgcn_mfma_f32_16x16x32_bf16(a[mf], bbv[nf], acc[mf][nf], 0, 0, 0);
        }
    }
    int p = n0 >> 10;
    int lgrp = lane >> 4;
    #pragma unroll
    for (int mf = 0; mf < 2; ++mf) {
        #pragma unroll
        for (int nf = 0; nf < 4; ++nf) {
            int col = n0 + wc * 64 + nf * 16 + lane15;
            int ch = col & 1023;
            int h = ch >> 6, dh = ch & 63;
            int row0 = m0 + wr * 32 + mf * 16 + lgrp * 4;
            if (p == 0 || p == 1) {
                unsigned short* base = (p == 0) ? Qb : Kb;
                float scl = (p == 0) ? 0.125f : 1.0f;
                #pragma unroll
                for (int rr = 0; rr < 4; ++rr) {
                    int rowx = row0 + rr;
                    int b = rowx >> 9, n = rowx & 511;
                    base[(((long)(b * 16 + h)) * 512 + n) * 64 + dh] = f2b(acc[mf][nf][rr] * scl);
                }
            } else if (p == 2) {
                int b = row0 >> 9, n = row0 & 511;
                ushort4 v;
                v.x = f2b(acc[mf][nf][0]); v.y = f2b(acc[mf][nf][1]);
                v.z = f2b(acc[mf][nf][2]); v.w = f2b(acc[mf][nf][3]);
                *(ushort4*)&Vt[(((long)(b * 16 + h)) * 64 + dh) * 512 + n] = v;
            } else {
                #pragma unroll
                for (int rr = 0; rr < 4; ++rr) {
                    int rowx = row0 + rr;
                    Xg[(long)rowx * 1024 + ch] = f2b(acc[mf][nf][rr]);
                }
            }
        }
    }
}

// ---------------- fused flash attention -------------------------------------
// v4: pad-free XOR-swizzled LDS + Ps/Oscr union -> 64.5 KB -> 2 blocks/CU.
__global__ __launch_bounds__(512) void k_flash(const unsigned short* __restrict__ Qb,
                                               const unsigned short* __restrict__ Kb,
                                               const unsigned short* __restrict__ Vt,
                                               const unsigned short* __restrict__ biasP,
                                               const unsigned short* __restrict__ Xg,
                                               unsigned short* __restrict__ Og) {
    __shared__ unsigned short Kt[2][64][64];   // 16 KB, swizzled
    __shared__ unsigned short Vs[2][64][64];   // 16 KB, swizzled
    __shared__ unsigned short Bt[2][64][64];   // 16 KB, swizzled
    __shared__ char PsOscr[16384];             // Ps (main loop) ∪ Oscr (merge)
    __shared__ float Mscr[4][16], Lscr[4][16];
    unsigned short (*Ps)[16][64] = (unsigned short(*)[16][64])PsOscr;
    float (*Oscr)[16][64] = (float(*)[16][64])PsOscr;
    int bh = blockIdx.y;
    int b = bh >> 4, h = bh & 15;
    int i0 = blockIdx.x * 64;
    int t = threadIdx.x, w = t >> 6, lane = t & 63;
    int g = w & 3, jg = w >> 2;
    int lane15 = lane & 15, lgrp = lane >> 4;
    int tl = t & 255;
    int rs_ = tl >> 3, cs_ = tl & 7;

    bf16x8 qf[2];
    #pragma unroll
    for (int kk = 0; kk < 2; ++kk)
        qf[kk] = *(const bf16x8*)&Qb[((long)bh * 512 + i0 + g * 16 + lane15) * 64 + kk * 32 + lgrp * 8];

    float m_run = -1e30f, l_run = 0.f;
    f32x4 o[4] = {};

    for (int jtl = 0; jtl < 4; ++jtl) {
        int j0 = (jg * 4 + jtl) * 64;
        __syncthreads();
        {
            int r2 = rs_ + 32;
            *(uint4*)((char*)&Kt[jg][rs_][0] + SW(rs_, cs_ * 16)) =
                *(const uint4*)&Kb[((long)bh * 512 + j0 + rs_) * 64 + cs_ * 8];
            *(uint4*)((char*)&Vs[jg][rs_][0] + SW(rs_, cs_ * 16)) =
                *(const uint4*)&Vt[((long)bh * 64 + rs_) * 512 + j0 + cs_ * 8];
            *(uint4*)((char*)&Bt[jg][rs_][0] + SW(rs_, cs_ * 16)) =
                *(const uint4*)&biasP[((long)bh * 512 + i0 + rs_) * 512 + j0 + cs_ * 8];
            *(uint4*)((char*)&Kt[jg][r2][0] + SW(r2, cs_ * 16)) =
                *(const uint4*)&Kb[((long)bh * 512 + j0 + r2) * 64 + cs_ * 8];
            *(uint4*)((char*)&Vs[jg][r2][0] + SW(r2, cs_ * 16)) =
                *(const uint4*)&Vt[((long)bh * 64 + r2) * 512 + j0 + cs_ * 8];
            *(uint4*)((char*)&Bt[jg][r2][0] + SW(r2, cs_ * 16)) =
                *(const uint4*)&biasP[((long)bh * 512 + i0 + r2) * 512 + j0 + cs_ * 8];
        }
        __syncthreads();

        f32x4 s[4];
        #pragma unroll
        for (int nf = 0; nf < 4; ++nf) {
            f32x4 z = {};
            #pragma unroll
            for (int kk = 0; kk < 2; ++kk) {
                bf16x8 af = *(const bf16x8*)((const char*)&Kt[jg][nf * 16 + lane15][0] +
                                             SW(lane15, kk * 64 + lgrp * 16));
                z = __builtin_amdgcn_mfma_f32_16x16x32_bf16(af, qf[kk], z, 0, 0, 0);
            }
            s[nf] = z;
        }
        #pragma unroll
        for (int nf = 0; nf < 4; ++nf) {
            ushort4 bv = *(const ushort4*)((const char*)&Bt[jg][g * 16 + lane15][0] +
                                           SW(lane15, nf * 32 + lgrp * 8));
            s[nf][0] += b2f(bv.x); s[nf][1] += b2f(bv.y);
            s[nf][2] += b2f(bv.z); s[nf][3] += b2f(bv.w);
        }

        float pmax = s[0][0];
        #pragma unroll
        for (int nf = 0; nf < 4; ++nf)
            #pragma unroll
            for (int rr = 0; rr < 4; ++rr) pmax = fmaxf(pmax, s[nf][rr]);
        pmax = fmaxf(pmax, __shfl_xor(pmax, 16));
        pmax = fmaxf(pmax, __shfl_xor(pmax, 32));
        float m_new = fmaxf(m_run, pmax);
        float scale = __expf(m_run - m_new);
        float psum = 0.f;
        #pragma unroll
        for (int nf = 0; nf < 4; ++nf)
            #pragma unroll
            for (int rr = 0; rr < 4; ++rr) {
                s[nf][rr] = __expf(s[nf][rr] - m_new);
                psum += s[nf][rr];
            }
        psum += __shfl_xor(psum, 16);
        psum += __shfl_xor(psum, 32);
        l_run = l_run * scale + psum;
        m_run = m_new;
        #pragma unroll
        for (int rr = 0; rr < 4; ++rr) {
            float sc = __shfl(scale, lgrp * 4 + rr);
            #pragma unroll
            for (int nf = 0; nf < 4; ++nf) o[nf][rr] *= sc;
        }
        #pragma unroll
        for (int nf = 0; nf < 4; ++nf) {
            ushort4 pv_;
            pv_.x = f2b(s[nf][0]); pv_.y = f2b(s[nf][1]);
            pv_.z = f2b(s[nf][2]); pv_.w = f2b(s[nf][3]);
            *(ushort4*)((char*)&Ps[w][lane15][0] + SW(lane15, nf * 32 + lgrp * 8)) = pv_;
        }
        #pragma unroll
        for (int kk = 0; kk < 2; ++kk) {
            bf16x8 pa = *(const bf16x8*)((const char*)&Ps[w][lane15][0] +
                                         SW(lane15, kk * 64 + lgrp * 16));
            #pragma unroll
            for (int nf = 0; nf < 4; ++nf) {
                bf16x8 vb = *(const bf16x8*)((const char*)&Vs[jg][nf * 16 + lane15][0] +
                                             SW(lane15, kk * 64 + lgrp * 16));
                o[nf] = __builtin_amdgcn_mfma_f32_16x16x32_bf16(pa, vb, o[nf], 0, 0, 0);
            }
        }
    }

    // split-softmax merge (Ps dead; Oscr overlays it)
    __syncthreads();
    if (jg == 1) {
        if (lane < 16) { Mscr[g][lane] = m_run; Lscr[g][lane] = l_run; }
        #pragma unroll
        for (int nf = 0; nf < 4; ++nf)
            #pragma unroll
            for (int rr = 0; rr < 4; ++rr)
                Oscr[g][lgrp * 4 + rr][nf * 16 + lane15] = o[nf][rr];
    }
    __syncthreads();
    if (jg == 0) {
        #pragma unroll
        for (int rr = 0; rr < 4; ++rr) {
            int row = lgrp * 4 + rr;
            float m1 = __shfl(m_run, row);
            float l1 = __shfl(l_run, row);
            float m2 = Mscr[g][row];
            float l2 = Lscr[g][row];
            float mm = fmaxf(m1, m2);
            float e1 = __expf(m1 - mm), e2 = __expf(m2 - mm);
            float inv = 1.f / (l1 * e1 + l2 * e2);
            long grow = (long)b * 512 + i0 + g * 16 + row;
            #pragma unroll
            for (int nf = 0; nf < 4; ++nf) {
                int dh = nf * 16 + lane15;
                float o2 = Oscr[g][row][dh];
                float val = (o[nf][rr] * e1 + o2 * e2) * inv;
                float xgv = b2f(Xg[grow * 1024 + h * 64 + dh]);
                float gate = 1.f / (1.f + __expf(-xgv));
                Og[grow * 1024 + h * 64 + dh] = f2b(val * gate);
            }
        }
    }
}

// ---------------- output GEMM: out = Og @ w_o (M=1024,N=384,K=1024) ---------
__global__ __launch_bounds__(256) void k_out(const unsigned short* __restrict__ Og,
                                             const unsigned short* __restrict__ Wot,
                                             float* __restrict__ out) {
    __shared__ unsigned short As[64][64 + PAD];
    __shared__ unsigned short Bs[64][64 + PAD];
    int m0 = blockIdx.x * 64, n0 = blockIdx.y * 64;
    int t = threadIdx.x, wave = t >> 6, lane = t & 63;
    int wr = wave >> 1, wc = wave & 1;
    int lane15 = lane & 15, kg = lane >> 4;
    f32x4 acc[2][2] = {};
    for (int k0 = 0; k0 < 1024; k0 += 64) {
        __syncthreads();
        {
            int r = t >> 2, qd = t & 3;
            const uint4* s1 = (const uint4*)(Og + (long)(m0 + r) * 1024 + k0 + qd * 16);
            uint4* d1 = (uint4*)&As[r][qd * 16];
            d1[0] = s1[0]; d1[1] = s1[1];
            const uint4* s2 = (const uint4*)(Wot + (long)(n0 + r) * 1024 + k0 + qd * 16);
            uint4* d2 = (uint4*)&Bs[r][qd * 16];
            d2[0] = s2[0]; d2[1] = s2[1];
        }
        __syncthreads();
        #pragma unroll
        for (int ks = 0; ks < 2; ++ks) {
            bf16x8 a[2], bbv[2];
            #pragma unroll
            for (int mf = 0; mf < 2; ++mf)
                a[mf] = *(const bf16x8*)&As[wr * 32 + mf * 16 + lane15][ks * 32 + kg * 8];
            #pragma unroll
            for (int nf = 0; nf < 2; ++nf)
                bbv[nf] = *(const bf16x8*)&Bs[wc * 32 + nf * 16 + lane15][ks * 32 + kg * 8];
            #pragma unroll
            for (int mf = 0; mf < 2; ++mf)
                #pragma unroll
                for (int nf = 0; nf < 2; ++nf)
                    acc[mf][nf] = __builtin_amdgcn_mfma_f32_16x16x32_bf16(a[mf], bbv[nf], acc[mf][nf], 0, 0, 0);
        }
    }
    int lgrp = lane >> 4;
    #pragma unroll
    for (int mf = 0; mf < 2; ++mf) {
        #pragma unroll
        for (int nf = 0; nf < 2; ++nf) {
            int col = n0 + wc * 32 + nf * 16 + lane15;
            int row0 = m0 + wr * 32 + mf * 16 + lgrp * 4;
            #pragma unroll
            for (int rr = 0; rr < 4; ++rr)
                out[(long)(row0 + rr) * DS_ + col] = acc[mf][nf][rr];
        }
    }
}

extern "C" void kernel_launch(void* const* d_in, const int* in_sizes, int n_in,
                              void* d_out, int out_size, void* d_ws, size_t ws_size,
                              hipStream_t stream) {
    const float* single = (const float*)d_in[0];
    const float* pw     = (const float*)d_in[1];
    const float* gamma  = (const float*)d_in[2];
    const float* beta   = (const float*)d_in[3];
    const float* wb     = (const float*)d_in[4];
    const float* abb    = (const float*)d_in[5];
    const float* wq     = (const float*)d_in[6];
    const float* wk     = (const float*)d_in[7];
    const float* wv     = (const float*)d_in[8];
    const float* wg     = (const float*)d_in[9];
    const float* wo     = (const float*)d_in[10];
    float* out = (float*)d_out;
    char* ws = (char*)d_ws;

    unsigned short* SP  = (unsigned short*)(ws);                 // 16 MB bias [b][h][i][j]
    unsigned short* Qb  = (unsigned short*)(ws + 16777216);      // 2 MB (pre-scaled 0.125)
    unsigned short* Kb  = (unsigned short*)(ws + 18874368);      // 2 MB
    unsigned short* Vt  = (unsigned short*)(ws + 20971520);      // 2 MB [b][h][dh][n]
    unsigned short* Xg  = (unsigned short*)(ws + 23068672);      // 2 MB
    unsigned short* Og  = (unsigned short*)(ws + 25165824);      // 2 MB
    unsigned short* Wt  = (unsigned short*)(ws + 27262976);      // 3 MB [4*1024][384]
    unsigned short* Wot = (unsigned short*)(ws + 30408704);      // 0.75 MB [384][1024]

    k_pre<<<2944, 256, 0, stream>>>(pw, abb, gamma, beta, wb,
                                    wq, wk, wv, wg, wo, Wt, Wot, SP);
    k_proj<<<dim3(16, 32), 256, 0, stream>>>(single, Wt, Qb, Kb, Vt, Xg);
    k_flash<<<dim3(8, 32), 512, 0, stream>>>(Qb, Kb, Vt, SP, Xg, Og);
    k_out<<<dim3(16, 6), 256, 0, stream>>>(Og, Wot, out);
}

// Round 19
// 106.633 us; speedup vs baseline: 1.5595x; 1.0581x over previous
//
#include <hip/hip_runtime.h>
#include <hip/hip_bf16.h>

#define B_ 2
#define N_ 512
#define DS_ 384
#define DP_ 128
#define H_ 16
#define DH_ 64
#define DI_ 1024
#define MAXSEQ 2048
#define PAD 8

typedef float f32x4 __attribute__((ext_vector_type(4)));
typedef short bf16x8 __attribute__((ext_vector_type(8)));
typedef unsigned int u32x4 __attribute__((ext_vector_type(4)));

__device__ __forceinline__ unsigned short f2b(float f) {
    unsigned int u = __builtin_bit_cast(unsigned int, f);
    u += 0x7FFFu + ((u >> 16) & 1u);
    return (unsigned short)(u >> 16);
}
__device__ __forceinline__ float b2f(unsigned short s) {
    unsigned int u = ((unsigned int)s) << 16;
    return __builtin_bit_cast(float, u);
}

// XOR swizzle: byte-column ^ ((row&7)<<4). Applied on BOTH write and read.
#define SW(row, bc) ((bc) ^ (((row) & 7) << 4))
// output-buffer swizzle (within a 256B h-row): byte ^ ((h&7)<<5), bits 5-7 only
#define SWO(h, bc) ((bc) ^ (((h) & 7) << 5))

// ---- k_pre: bias wave-streams (bid<1024) + weight transposes (bid>=1024) ---
// Bias v9: barrier-free per-wave pipeline (v8) + DECOUPLED COALESCED WRITES.
// Theory: the ~3.3TB/s read plateau was never read-side — it was ~2M scattered
// 32B partial-line writes ([b][h][i][j] scatter) interleaved with the read
// stream forcing HBM read<->write turnarounds. v9 buffers each wave's 4KB of
// results in private LDS and writes ONE bulk burst of 256B-contiguous
// segments at the end; the streaming loop is pure read+compute.
__global__ __launch_bounds__(256) void k_pre(const float* __restrict__ pw,
                                             const float* __restrict__ abb,
                                             const float* __restrict__ gamma,
                                             const float* __restrict__ beta,
                                             const float* __restrict__ wb,
                                             const float* __restrict__ wq,
                                             const float* __restrict__ wk,
                                             const float* __restrict__ wv,
                                             const float* __restrict__ wg,
                                             const float* __restrict__ wo,
                                             unsigned short* __restrict__ Wt,
                                             unsigned short* __restrict__ Wot,
                                             unsigned short* __restrict__ biasP) {
    __shared__ float Xs4[4][16 * 128];          // 4 x 8KB private stage tiles
    __shared__ unsigned short Os4[4][2048];     // 4 x 4KB private output buffers
    __shared__ float rsum4[4][16] __attribute__((aligned(16)));
    __shared__ float rsq4[4][16] __attribute__((aligned(16)));
    int bid = blockIdx.x;
    int t = threadIdx.x;

    if (bid >= 1024) {                  // ---- transpose path ----
        int tid = bid - 1024;
        int z = tid / 384, r = tid % 384;
        const float* in; unsigned short* out; int C, Rr, c0, r0;
        if (z < 4) {
            in = (z == 0) ? wq : (z == 1) ? wk : (z == 2) ? wv : wg;
            out = Wt + (long)z * 1024 * 384;
            C = 1024; Rr = 384;
            c0 = (r & 31) * 32; r0 = (r >> 5) * 32;
        } else {
            in = wo; out = Wot; C = 384; Rr = 1024;
            c0 = (r % 12) * 32; r0 = (r / 12) * 32;
        }
        float (*tile)[33] = (float(*)[33])&Xs4[0][0];
        int tx = t & 31, ty = t >> 5;
        #pragma unroll
        for (int i = ty; i < 32; i += 8)
            tile[i][tx] = in[(long)(r0 + i) * C + (c0 + tx)];
        __syncthreads();
        #pragma unroll
        for (int i = ty; i < 32; i += 8)
            out[(long)(c0 + i) * Rr + (r0 + tx)] = f2b(tile[tx][i]);
        return;
    }

    // ---- bias path (no __syncthreads below this point) ----
    int w = t >> 6, lane = t & 63;
    int lane15 = lane & 15, kg = lane >> 4;

    // per-wave prep (L2-hot 8KB wb): gb[kk] + sh/th, shuffle-reduced
    float shp = 0.f, thp = 0.f;
    bf16x8 gb[4];
    #pragma unroll
    for (int kk = 0; kk < 4; ++kk) {
        bf16x8 a;
        unsigned short* ap = (unsigned short*)&a;
        #pragma unroll
        for (int e = 0; e < 8; ++e) {
            int d = kk * 32 + kg * 8 + e;
            float wv_ = wb[d * 16 + lane15];
            float gv = gamma[d];
            ap[e] = f2b(gv * wv_);
            shp = fmaf(gv, wv_, shp);
            thp = fmaf(beta[d], wv_, thp);
        }
        gb[kk] = a;
    }
    shp += __shfl_xor(shp, 16); shp += __shfl_xor(shp, 32);
    thp += __shfl_xor(thp, 16); thp += __shfl_xor(thp, 32);
    float sh = shp, th = thp;

    char* lds = (char*)&Xs4[w][0];              // private 8KB stage
    char* ldso = (char*)&Os4[w][0];             // private 4KB out buffer
    float* rsum = rsum4[w];
    float* rsq  = rsq4[w];
    long wstream = (long)bid * 4 + w;           // 0..4095 wave-streams
    long pbase = wstream * 128;                 // 128 consecutive flat rows
    int i_blk = (int)((pbase >> 9) & (N_ - 1));
    int jwave = (int)(pbase & (N_ - 1));        // multiple of 128
    long bb = pbase >> 18;
    const char* srcS = (const char*)pw + (wstream << 16);   // 64KB contiguous

    // preload sub-tile 0 (NT: stream-once, don't allocate)
    u32x4 rg[8];
    #pragma unroll
    for (int c = 0; c < 8; ++c)
        rg[c] = __builtin_nontemporal_load((const u32x4*)(srcS + c * 1024 + lane * 16));

    for (int s = 0; s < 8; ++s) {
        int j0 = jwave + s * 16;

        // stage to private LDS (swizzled); per-wave LDS is in-order
        #pragma unroll
        for (int c = 0; c < 8; ++c) {
            int L = c * 1024 + lane * 16;
            int row = L >> 9, b = L & 511;
            *(u32x4*)(lds + (row << 9) + (b ^ ((row & 7) << 4))) = rg[c];
        }
        // issue next sub-tile's loads NOW — in flight through compute
        if (s < 7) {
            const char* srcn = srcS + (s + 1) * 8192;
            #pragma unroll
            for (int c = 0; c < 8; ++c)
                rg[c] = __builtin_nontemporal_load((const u32x4*)(srcn + c * 1024 + lane * 16));
        }

        // fragments: row = lane15, swizzled read
        const char* rbase = lds + (lane15 << 9);
        int sw = (lane15 & 7) << 4;
        f32x4 xa[4], xb4[4];
        #pragma unroll
        for (int kk = 0; kk < 4; ++kk) {
            int b0 = kk * 128 + kg * 32;
            xa[kk]  = *(const f32x4*)(rbase + ((b0) ^ sw));
            xb4[kk] = *(const f32x4*)(rbase + ((b0 + 16) ^ sw));
        }
        float s_ = 0.f, q = 0.f;
        #pragma unroll
        for (int kk = 0; kk < 4; ++kk) {
            s_ += xa[kk][0] + xa[kk][1] + xa[kk][2] + xa[kk][3];
            s_ += xb4[kk][0] + xb4[kk][1] + xb4[kk][2] + xb4[kk][3];
            #pragma unroll
            for (int e = 0; e < 4; ++e) {
                q = fmaf(xa[kk][e], xa[kk][e], q);
                q = fmaf(xb4[kk][e], xb4[kk][e], q);
            }
        }
        s_ += __shfl_xor(s_, 16); s_ += __shfl_xor(s_, 32);
        q  += __shfl_xor(q, 16);  q  += __shfl_xor(q, 32);
        if (lane < 16) { rsum[lane15] = s_; rsq[lane15] = q; }

        f32x4 acc = {};
        #pragma unroll
        for (int kk = 0; kk < 4; ++kk) {
            bf16x8 a;
            unsigned short* ap = (unsigned short*)&a;
            ap[0] = f2b(xa[kk][0]);  ap[1] = f2b(xa[kk][1]);
            ap[2] = f2b(xa[kk][2]);  ap[3] = f2b(xa[kk][3]);
            ap[4] = f2b(xb4[kk][0]); ap[5] = f2b(xb4[kk][1]);
            ap[6] = f2b(xb4[kk][2]); ap[7] = f2b(xb4[kk][3]);
            acc = __builtin_amdgcn_mfma_f32_16x16x32_bf16(a, gb[kk], acc, 0, 0, 0);
        }
        // epilogue -> private LDS out buffer (NOT global): lane holds h=lane15,
        // tile-local j = kg*4 + rr  (logical byte off = s*32 + kg*8, swizzled)
        int jr = kg * 4;
        float4 rs = *(const float4*)&rsum[jr];
        float4 rq = *(const float4*)&rsq[jr];
        float4 av = *(const float4*)(abb + (long)i_blk * MAXSEQ + j0 + jr);
        ushort4 res;
        float mu, var;
        mu = rs.x * (1.f / DP_); var = fmaf(rq.x, 1.f / DP_, -mu * mu);
        res.x = f2b(fmaf(rsqrtf(var + 1e-5f), acc[0] - mu * sh, th + av.x));
        mu = rs.y * (1.f / DP_); var = fmaf(rq.y, 1.f / DP_, -mu * mu);
        res.y = f2b(fmaf(rsqrtf(var + 1e-5f), acc[1] - mu * sh, th + av.y));
        mu = rs.z * (1.f / DP_); var = fmaf(rq.z, 1.f / DP_, -mu * mu);
        res.z = f2b(fmaf(rsqrtf(var + 1e-5f), acc[2] - mu * sh, th + av.z));
        mu = rs.w * (1.f / DP_); var = fmaf(rq.w, 1.f / DP_, -mu * mu);
        res.w = f2b(fmaf(rsqrtf(var + 1e-5f), acc[3] - mu * sh, th + av.w));
        *(ushort4*)(ldso + lane15 * 256 + SWO(lane15, s * 32 + kg * 8)) = res;
    }

    // bulk coalesced write burst: 4 instrs, each 4 h-planes x 256B segments
    #pragma unroll
    for (int it = 0; it < 4; ++it) {
        int h = it * 4 + (lane >> 4);
        int jj = (lane & 15) * 8;               // 8 j's = 16B per lane
        u32x4 v = *(const u32x4*)(ldso + h * 256 + SWO(h, jj * 2));
        *(u32x4*)(biasP + ((bb * H_ + h) * N_ + i_blk) * N_ + jwave + jj) = v;
    }
}

// ---------------- QKVG projection GEMM (M=1024, N=4096, K=384) --------------
// 64x128 tiles, 512 blocks (2/CU). Q pre-scaled by 0.125.
__global__ __launch_bounds__(256) void k_proj(const float* __restrict__ X,
                                              const unsigned short* __restrict__ Wt,
                                              unsigned short* __restrict__ Qb,
                                              unsigned short* __restrict__ Kb,
                                              unsigned short* __restrict__ Vt,
                                              unsigned short* __restrict__ Xg) {
    __shared__ unsigned short As[64][64 + PAD];
    __shared__ unsigned short Bs[128][64 + PAD];
    int m0 = blockIdx.x * 64;
    int n0 = blockIdx.y * 128;
    int t = threadIdx.x;
    int wave = t >> 6, lane = t & 63;
    int wr = wave >> 1, wc = wave & 1;
    int lane15 = lane & 15, kg = lane >> 4;
    int rA = t >> 2, qA = t & 3;
    int rB = t >> 1, hB = t & 1;
    f32x4 acc[2][4] = {};
    for (int k0 = 0; k0 < DS_; k0 += 64) {
        __syncthreads();
        {
            const float4* srcA = (const float4*)(X + (long)(m0 + rA) * DS_ + k0 + qA * 16);
            unsigned short* dstA = &As[rA][qA * 16];
            #pragma unroll
            for (int ii = 0; ii < 4; ++ii) {
                float4 v = srcA[ii];
                dstA[ii * 4 + 0] = f2b(v.x); dstA[ii * 4 + 1] = f2b(v.y);
                dstA[ii * 4 + 2] = f2b(v.z); dstA[ii * 4 + 3] = f2b(v.w);
            }
            const uint4* srcB = (const uint4*)(Wt + (long)(n0 + rB) * DS_ + k0 + hB * 32);
            uint4* dstB = (uint4*)&Bs[rB][hB * 32];
            dstB[0] = srcB[0]; dstB[1] = srcB[1]; dstB[2] = srcB[2]; dstB[3] = srcB[3];
        }
        __syncthreads();
        #pragma unroll
        for (int ks = 0; ks < 2; ++ks) {
            bf16x8 a[2], bbv[4];
            #pragma unroll
            for (int mf = 0; mf < 2; ++mf)
                a[mf] = *(const bf16x8*)&As[wr * 32 + mf * 16 + lane15][ks * 32 + kg * 8];
            #pragma unroll
            for (int nf = 0; nf < 4; ++nf)
                bbv[nf] = *(const bf16x8*)&Bs[wc * 64 + nf * 16 + lane15][ks * 32 + kg * 8];
            #pragma unroll
            for (int mf = 0; mf < 2; ++mf)
                #pragma unroll
                for (int nf = 0; nf < 4; ++nf)
                    acc[mf][nf] = __builtin_amdgcn_mfma_f32_16x16x32_bf16(a[mf], bbv[nf], acc[mf][nf], 0, 0, 0);
        }
    }
    int p = n0 >> 10;
    int lgrp = lane >> 4;
    #pragma unroll
    for (int mf = 0; mf < 2; ++mf) {
        #pragma unroll
        for (int nf = 0; nf < 4; ++nf) {
            int col = n0 + wc * 64 + nf * 16 + lane15;
            int ch = col & 1023;
            int h = ch >> 6, dh = ch & 63;
            int row0 = m0 + wr * 32 + mf * 16 + lgrp * 4;
            if (p == 0 || p == 1) {
                unsigned short* base = (p == 0) ? Qb : Kb;
                float scl = (p == 0) ? 0.125f : 1.0f;
                #pragma unroll
                for (int rr = 0; rr < 4; ++rr) {
                    int rowx = row0 + rr;
                    int b = rowx >> 9, n = rowx & 511;
                    base[(((long)(b * 16 + h)) * 512 + n) * 64 + dh] = f2b(acc[mf][nf][rr] * scl);
                }
            } else if (p == 2) {
                int b = row0 >> 9, n = row0 & 511;
                ushort4 v;
                v.x = f2b(acc[mf][nf][0]); v.y = f2b(acc[mf][nf][1]);
                v.z = f2b(acc[mf][nf][2]); v.w = f2b(acc[mf][nf][3]);
                *(ushort4*)&Vt[(((long)(b * 16 + h)) * 64 + dh) * 512 + n] = v;
            } else {
                #pragma unroll
                for (int rr = 0; rr < 4; ++rr) {
                    int rowx = row0 + rr;
                    Xg[(long)rowx * 1024 + ch] = f2b(acc[mf][nf][rr]);
                }
            }
        }
    }
}

// ---------------- fused flash attention -------------------------------------
// v4: pad-free XOR-swizzled LDS + Ps/Oscr union -> 64.5 KB -> 2 blocks/CU.
__global__ __launch_bounds__(512) void k_flash(const unsigned short* __restrict__ Qb,
                                               const unsigned short* __restrict__ Kb,
                                               const unsigned short* __restrict__ Vt,
                                               const unsigned short* __restrict__ biasP,
                                               const unsigned short* __restrict__ Xg,
                                               unsigned short* __restrict__ Og) {
    __shared__ unsigned short Kt[2][64][64];   // 16 KB, swizzled
    __shared__ unsigned short Vs[2][64][64];   // 16 KB, swizzled
    __shared__ unsigned short Bt[2][64][64];   // 16 KB, swizzled
    __shared__ char PsOscr[16384];             // Ps (main loop) ∪ Oscr (merge)
    __shared__ float Mscr[4][16], Lscr[4][16];
    unsigned short (*Ps)[16][64] = (unsigned short(*)[16][64])PsOscr;
    float (*Oscr)[16][64] = (float(*)[16][64])PsOscr;
    int bh = blockIdx.y;
    int b = bh >> 4, h = bh & 15;
    int i0 = blockIdx.x * 64;
    int t = threadIdx.x, w = t >> 6, lane = t & 63;
    int g = w & 3, jg = w >> 2;
    int lane15 = lane & 15, lgrp = lane >> 4;
    int tl = t & 255;
    int rs_ = tl >> 3, cs_ = tl & 7;

    bf16x8 qf[2];
    #pragma unroll
    for (int kk = 0; kk < 2; ++kk)
        qf[kk] = *(const bf16x8*)&Qb[((long)bh * 512 + i0 + g * 16 + lane15) * 64 + kk * 32 + lgrp * 8];

    float m_run = -1e30f, l_run = 0.f;
    f32x4 o[4] = {};

    for (int jtl = 0; jtl < 4; ++jtl) {
        int j0 = (jg * 4 + jtl) * 64;
        __syncthreads();
        {
            int r2 = rs_ + 32;
            *(uint4*)((char*)&Kt[jg][rs_][0] + SW(rs_, cs_ * 16)) =
                *(const uint4*)&Kb[((long)bh * 512 + j0 + rs_) * 64 + cs_ * 8];
            *(uint4*)((char*)&Vs[jg][rs_][0] + SW(rs_, cs_ * 16)) =
                *(const uint4*)&Vt[((long)bh * 64 + rs_) * 512 + j0 + cs_ * 8];
            *(uint4*)((char*)&Bt[jg][rs_][0] + SW(rs_, cs_ * 16)) =
                *(const uint4*)&biasP[((long)bh * 512 + i0 + rs_) * 512 + j0 + cs_ * 8];
            *(uint4*)((char*)&Kt[jg][r2][0] + SW(r2, cs_ * 16)) =
                *(const uint4*)&Kb[((long)bh * 512 + j0 + r2) * 64 + cs_ * 8];
            *(uint4*)((char*)&Vs[jg][r2][0] + SW(r2, cs_ * 16)) =
                *(const uint4*)&Vt[((long)bh * 64 + r2) * 512 + j0 + cs_ * 8];
            *(uint4*)((char*)&Bt[jg][r2][0] + SW(r2, cs_ * 16)) =
                *(const uint4*)&biasP[((long)bh * 512 + i0 + r2) * 512 + j0 + cs_ * 8];
        }
        __syncthreads();

        f32x4 s[4];
        #pragma unroll
        for (int nf = 0; nf < 4; ++nf) {
            f32x4 z = {};
            #pragma unroll
            for (int kk = 0; kk < 2; ++kk) {
                bf16x8 af = *(const bf16x8*)((const char*)&Kt[jg][nf * 16 + lane15][0] +
                                             SW(lane15, kk * 64 + lgrp * 16));
                z = __builtin_amdgcn_mfma_f32_16x16x32_bf16(af, qf[kk], z, 0, 0, 0);
            }
            s[nf] = z;
        }
        #pragma unroll
        for (int nf = 0; nf < 4; ++nf) {
            ushort4 bv = *(const ushort4*)((const char*)&Bt[jg][g * 16 + lane15][0] +
                                           SW(lane15, nf * 32 + lgrp * 8));
            s[nf][0] += b2f(bv.x); s[nf][1] += b2f(bv.y);
            s[nf][2] += b2f(bv.z); s[nf][3] += b2f(bv.w);
        }

        float pmax = s[0][0];
        #pragma unroll
        for (int nf = 0; nf < 4; ++nf)
            #pragma unroll
            for (int rr = 0; rr < 4; ++rr) pmax = fmaxf(pmax, s[nf][rr]);
        pmax = fmaxf(pmax, __shfl_xor(pmax, 16));
        pmax = fmaxf(pmax, __shfl_xor(pmax, 32));
        float m_new = fmaxf(m_run, pmax);
        float scale = __expf(m_run - m_new);
        float psum = 0.f;
        #pragma unroll
        for (int nf = 0; nf < 4; ++nf)
            #pragma unroll
            for (int rr = 0; rr < 4; ++rr) {
                s[nf][rr] = __expf(s[nf][rr] - m_new);
                psum += s[nf][rr];
            }
        psum += __shfl_xor(psum, 16);
        psum += __shfl_xor(psum, 32);
        l_run = l_run * scale + psum;
        m_run = m_new;
        #pragma unroll
        for (int rr = 0; rr < 4; ++rr) {
            float sc = __shfl(scale, lgrp * 4 + rr);
            #pragma unroll
            for (int nf = 0; nf < 4; ++nf) o[nf][rr] *= sc;
        }
        #pragma unroll
        for (int nf = 0; nf < 4; ++nf) {
            ushort4 pv_;
            pv_.x = f2b(s[nf][0]); pv_.y = f2b(s[nf][1]);
            pv_.z = f2b(s[nf][2]); pv_.w = f2b(s[nf][3]);
            *(ushort4*)((char*)&Ps[w][lane15][0] + SW(lane15, nf * 32 + lgrp * 8)) = pv_;
        }
        #pragma unroll
        for (int kk = 0; kk < 2; ++kk) {
            bf16x8 pa = *(const bf16x8*)((const char*)&Ps[w][lane15][0] +
                                         SW(lane15, kk * 64 + lgrp * 16));
            #pragma unroll
            for (int nf = 0; nf < 4; ++nf) {
                bf16x8 vb = *(const bf16x8*)((const char*)&Vs[jg][nf * 16 + lane15][0] +
                                             SW(lane15, kk * 64 + lgrp * 16));
                o[nf] = __builtin_amdgcn_mfma_f32_16x16x32_bf16(pa, vb, o[nf], 0, 0, 0);
            }
        }
    }

    // split-softmax merge (Ps dead; Oscr overlays it)
    __syncthreads();
    if (jg == 1) {
        if (lane < 16) { Mscr[g][lane] = m_run; Lscr[g][lane] = l_run; }
        #pragma unroll
        for (int nf = 0; nf < 4; ++nf)
            #pragma unroll
            for (int rr = 0; rr < 4; ++rr)
                Oscr[g][lgrp * 4 + rr][nf * 16 + lane15] = o[nf][rr];
    }
    __syncthreads();
    if (jg == 0) {
        #pragma unroll
        for (int rr = 0; rr < 4; ++rr) {
            int row = lgrp * 4 + rr;
            float m1 = __shfl(m_run, row);
            float l1 = __shfl(l_run, row);
            float m2 = Mscr[g][row];
            float l2 = Lscr[g][row];
            float mm = fmaxf(m1, m2);
            float e1 = __expf(m1 - mm), e2 = __expf(m2 - mm);
            float inv = 1.f / (l1 * e1 + l2 * e2);
            long grow = (long)b * 512 + i0 + g * 16 + row;
            #pragma unroll
            for (int nf = 0; nf < 4; ++nf) {
                int dh = nf * 16 + lane15;
                float o2 = Oscr[g][row][dh];
                float val = (o[nf][rr] * e1 + o2 * e2) * inv;
                float xgv = b2f(Xg[grow * 1024 + h * 64 + dh]);
                float gate = 1.f / (1.f + __expf(-xgv));
                Og[grow * 1024 + h * 64 + dh] = f2b(val * gate);
            }
        }
    }
}

// ---------------- output GEMM: out = Og @ w_o (M=1024,N=384,K=1024) ---------
__global__ __launch_bounds__(256) void k_out(const unsigned short* __restrict__ Og,
                                             const unsigned short* __restrict__ Wot,
                                             float* __restrict__ out) {
    __shared__ unsigned short As[64][64 + PAD];
    __shared__ unsigned short Bs[64][64 + PAD];
    int m0 = blockIdx.x * 64, n0 = blockIdx.y * 64;
    int t = threadIdx.x, wave = t >> 6, lane = t & 63;
    int wr = wave >> 1, wc = wave & 1;
    int lane15 = lane & 15, kg = lane >> 4;
    f32x4 acc[2][2] = {};
    for (int k0 = 0; k0 < 1024; k0 += 64) {
        __syncthreads();
        {
            int r = t >> 2, qd = t & 3;
            const uint4* s1 = (const uint4*)(Og + (long)(m0 + r) * 1024 + k0 + qd * 16);
            uint4* d1 = (uint4*)&As[r][qd * 16];
            d1[0] = s1[0]; d1[1] = s1[1];
            const uint4* s2 = (const uint4*)(Wot + (long)(n0 + r) * 1024 + k0 + qd * 16);
            uint4* d2 = (uint4*)&Bs[r][qd * 16];
            d2[0] = s2[0]; d2[1] = s2[1];
        }
        __syncthreads();
        #pragma unroll
        for (int ks = 0; ks < 2; ++ks) {
            bf16x8 a[2], bbv[2];
            #pragma unroll
            for (int mf = 0; mf < 2; ++mf)
                a[mf] = *(const bf16x8*)&As[wr * 32 + mf * 16 + lane15][ks * 32 + kg * 8];
            #pragma unroll
            for (int nf = 0; nf < 2; ++nf)
                bbv[nf] = *(const bf16x8*)&Bs[wc * 32 + nf * 16 + lane15][ks * 32 + kg * 8];
            #pragma unroll
            for (int mf = 0; mf < 2; ++mf)
                #pragma unroll
                for (int nf = 0; nf < 2; ++nf)
                    acc[mf][nf] = __builtin_amdgcn_mfma_f32_16x16x32_bf16(a[mf], bbv[nf], acc[mf][nf], 0, 0, 0);
        }
    }
    int lgrp = lane >> 4;
    #pragma unroll
    for (int mf = 0; mf < 2; ++mf) {
        #pragma unroll
        for (int nf = 0; nf < 2; ++nf) {
            int col = n0 + wc * 32 + nf * 16 + lane15;
            int row0 = m0 + wr * 32 + mf * 16 + lgrp * 4;
            #pragma unroll
            for (int rr = 0; rr < 4; ++rr)
                out[(long)(row0 + rr) * DS_ + col] = acc[mf][nf][rr];
        }
    }
}

extern "C" void kernel_launch(void* const* d_in, const int* in_sizes, int n_in,
                              void* d_out, int out_size, void* d_ws, size_t ws_size,
                              hipStream_t stream) {
    const float* single = (const float*)d_in[0];
    const float* pw     = (const float*)d_in[1];
    const float* gamma  = (const float*)d_in[2];
    const float* beta   = (const float*)d_in[3];
    const float* wb     = (const float*)d_in[4];
    const float* abb    = (const float*)d_in[5];
    const float* wq     = (const float*)d_in[6];
    const float* wk     = (const float*)d_in[7];
    const float* wv     = (const float*)d_in[8];
    const float* wg     = (const float*)d_in[9];
    const float* wo     = (const float*)d_in[10];
    float* out = (float*)d_out;
    char* ws = (char*)d_ws;

    unsigned short* SP  = (unsigned short*)(ws);                 // 16 MB bias [b][h][i][j]
    unsigned short* Qb  = (unsigned short*)(ws + 16777216);      // 2 MB (pre-scaled 0.125)
    unsigned short* Kb  = (unsigned short*)(ws + 18874368);      // 2 MB
    unsigned short* Vt  = (unsigned short*)(ws + 20971520);      // 2 MB [b][h][dh][n]
    unsigned short* Xg  = (unsigned short*)(ws + 23068672);      // 2 MB
    unsigned short* Og  = (unsigned short*)(ws + 25165824);      // 2 MB
    unsigned short* Wt  = (unsigned short*)(ws + 27262976);      // 3 MB [4*1024][384]
    unsigned short* Wot = (unsigned short*)(ws + 30408704);      // 0.75 MB [384][1024]

    k_pre<<<2944, 256, 0, stream>>>(pw, abb, gamma, beta, wb,
                                    wq, wk, wv, wg, wo, Wt, Wot, SP);
    k_proj<<<dim3(16, 32), 256, 0, stream>>>(single, Wt, Qb, Kb, Vt, Xg);
    k_flash<<<dim3(8, 32), 512, 0, stream>>>(Qb, Kb, Vt, SP, Xg, Og);
    k_out<<<dim3(16, 6), 256, 0, stream>>>(Og, Wot, out);
}